// Round 13
// baseline (1797.906 us; speedup 1.0000x reference)
//
#include <hip/hip_runtime.h>

// MultilayerGRU — reference's indexing bug makes every (b,t) independent:
// 7 chained GEMMs over a 65536x512 activation matrix.
// Round 13: LDS-FREE direct-to-register GEMM. Evidence: R4/R7/R9/R11/R12 all
// converge to ~15.5 B/cyc/CU of global_load_lds ingest (1.57GB staged -> 165µs
// = measured) regardless of schedule. Fragment loads direct from global are
// 16 rows x 64B contiguous per wave-load -> L2-direct at ~60 B/cyc/CU (m56),
// 4x the ingest rate. k-loop = pure register dataflow (reg dbuf, no barriers,
// no LDS). LDS kept only for epilogue haux tiling. z-sigmoid back in gates
// (R12's move regressed updates).

typedef __attribute__((ext_vector_type(4))) float f32x4;
typedef __attribute__((ext_vector_type(8))) __bf16 bf16x8;

#define NROWS 65536          // B*S
#define HID_OFF 33554432ull  // B*S*O floats, start of hidden_out in d_out

__device__ __forceinline__ void gload16(const void* g, void* l) {
  __builtin_amdgcn_global_load_lds((const __attribute__((address_space(1))) void*)g,
                                   (__attribute__((address_space(3))) void*)l,
                                   16, 0, 0);
}
__device__ __forceinline__ float sigmoidf_(float x) { return 1.f / (1.f + __expf(-x)); }
__device__ __forceinline__ float tanh_fast(float x) {
  const float e = __expf(2.f * x);
  return 1.f - 2.f / (e + 1.f);
}

// Stage a 128x128 bf16 tile of haux (512-col row-major) into 32KB LDS.
__device__ __forceinline__ void stage_ht(const __bf16* __restrict__ src,
                                         __bf16* Ht, int w, int lane) {
#pragma unroll
  for (int i = 0; i < 8; ++i) {
    const int s0 = i * 256 + w * 64;   // 16B chunks, 16 per row
    const int s = s0 + lane;
    const int row = s >> 4, cc = s & 15;
    gload16(src + (size_t)row * 512 + cc * 8, Ht + s0 * 8);
  }
  asm volatile("s_waitcnt vmcnt(0)");
  __builtin_amdgcn_sched_barrier(0);
  __builtin_amdgcn_s_barrier();
  __builtin_amdgcn_sched_barrier(0);
}

// EPI: 0 = gates (N=1536: z|r|gpart), 1 = update (N=512), 2 = out (N=512)
template<int EPI, bool L0>
__global__ __launch_bounds__(256, 3) void gemm13(
    const __bf16* __restrict__ A,     // M x 512 row-major
    const __bf16* __restrict__ Bt,    // N x 512 (pre-transposed weights)
    int tiles_n, int row_off,
    const float* __restrict__ bias,
    const float* __restrict__ cterm,  // L0 gates: 64 x 1024 fp32
    const float* __restrict__ h0f,    // L0: hidden_state base (B x 3*512)
    const __bf16* __restrict__ haux,  // L>=1: h row-major
    const __bf16* __restrict__ zf,    // fragment buffer (EPI0 write / EPI1 read)
    const __bf16* __restrict__ gf,    // fragment buffer (EPI0 write / EPI1 read)
    __bf16* __restrict__ o_rh,        // EPI0: r*h row-major
    __bf16* __restrict__ o_h,         // EPI1: h row-major
    float* __restrict__ o_f)          // EPI1: hidden_out slot; EPI2: out
{
  __shared__ alignas(16) __bf16 smem[16384];   // 32KB, epilogue haux tile only

  const int tid = threadIdx.x, lane = tid & 63, w = tid >> 6;

  // T1: bijective XCD swizzle (m204)
  int bid = blockIdx.x;
  {
    const int nwg = gridDim.x;
    const int q = nwg >> 3, r = nwg & 7;
    const int x = bid & 7, rest = bid >> 3;
    bid = (x < r ? x * (q + 1) : r * (q + 1) + (x - r) * q) + rest;
  }
  const int tm = bid / tiles_n;
  const int tn = bid - tm * tiles_n;
  const size_t arow0 = (size_t)tm * 128;
  const int brow0 = tn * 128;

  const int wr = (w >> 1) * 64;
  const int wc = (w & 1) * 64;

  // direct fragment base pointers: lane -> (row = base + lane&15, k-chunk = lane>>4)
  // wave-load = 16 rows x 64B contiguous -> 16 full cache lines (L2-friendly)
  const __bf16* const Ap = A  + (arow0 + wr + (lane & 15)) * 512 + (lane >> 4) * 8;
  const __bf16* const Bp = Bt + ((size_t)brow0 + wc + (lane & 15)) * 512 + (lane >> 4) * 8;

  f32x4 acc[4][4];
  const f32x4 zz = {0.f, 0.f, 0.f, 0.f};
#pragma unroll
  for (int i = 0; i < 4; ++i)
#pragma unroll
    for (int j = 0; j < 4; ++j) acc[i][j] = zz;

  bf16x8 a0[4], b0[4], a1[4], b1[4];

  auto ldfrag = [&](int t, bf16x8 (&fa)[4], bf16x8 (&fb)[4]) {
#pragma unroll
    for (int i = 0; i < 4; ++i) {
      fa[i] = *(const bf16x8*)(Ap + i * 8192 + t * 32);
      fb[i] = *(const bf16x8*)(Bp + i * 8192 + t * 32);
    }
  };
  auto domfma = [&](bf16x8 (&fa)[4], bf16x8 (&fb)[4]) {
#pragma unroll
    for (int mi = 0; mi < 4; ++mi)
#pragma unroll
      for (int ni = 0; ni < 4; ++ni)
        acc[mi][ni] = __builtin_amdgcn_mfma_f32_16x16x32_bf16(fa[mi], fb[ni], acc[mi][ni], 0, 0, 0);
  };

  // k-loop: 16 steps of K=32; register double-buffer, no LDS, no barriers.
  ldfrag(0, a0, b0);
#pragma unroll 1
  for (int t = 0; t < 16; t += 2) {
    ldfrag(t + 1, a1, b1);          // t+1 <= 15 always
    domfma(a0, b0);                 // tile t
    if (t + 2 < 16) ldfrag(t + 2, a0, b0);
    domfma(a1, b1);                 // tile t+1
  }

  // ---------------- epilogues ----------------
  const int fcol = lane & 15;
  const int frow = (lane >> 4) * 4;
  const int bb0 = (row_off + (int)arow0) >> 10;  // batch idx, uniform per tile

  if (EPI == 0) {
    if (tn < 4) {
      // z quadrant -> sigmoid, fragment-order store
      const size_t foff = ((size_t)(tm * 4 + tn)) * 16384 + (size_t)tid * 64;
      __bf16* zw = (__bf16*)zf;
#pragma unroll
      for (int mi = 0; mi < 4; ++mi) {
        bf16x8 p0, p1;
#pragma unroll
        for (int ni = 0; ni < 4; ++ni)
#pragma unroll
          for (int j = 0; j < 4; ++j) {
            const int gcol = brow0 + wc + ni * 16 + fcol;
            float c = acc[mi][ni][j] + bias[gcol];
            if (L0) c += cterm[bb0 * 1024 + gcol];
            const float v = sigmoidf_(c);
            const int idx = ni * 4 + j;
            if (idx < 8) p0[idx] = (__bf16)v; else p1[idx - 8] = (__bf16)v;
          }
        *(bf16x8*)(zw + foff + mi * 16) = p0;
        *(bf16x8*)(zw + foff + mi * 16 + 8) = p1;
      }
    } else if (tn < 8) {
      // r quadrant -> r*h row-major (h LDS-tiled for L>=1)
      if (!L0) stage_ht(haux + arow0 * 512 + (tn - 4) * 128, smem, w, lane);
#pragma unroll
      for (int mi = 0; mi < 4; ++mi)
#pragma unroll
        for (int ni = 0; ni < 4; ++ni)
#pragma unroll
          for (int j = 0; j < 4; ++j) {
            const int rloc = (int)arow0 + wr + mi * 16 + frow + j;
            const int gcol = brow0 + wc + ni * 16 + fcol;
            const int nn = gcol - 512;
            float c = acc[mi][ni][j] + bias[gcol];
            if (L0) c += cterm[bb0 * 1024 + gcol];
            const float rv = sigmoidf_(c);
            const float h = L0 ? h0f[bb0 * 1536 + nn]
                               : (float)smem[(wr + mi * 16 + frow + j) * 128 + wc + ni * 16 + fcol];
            o_rh[(size_t)rloc * 512 + nn] = (__bf16)(rv * h);
          }
    } else {
      // g-partial quadrant -> fragment-order store (raw, no activation)
      const size_t foff = ((size_t)(tm * 4 + (tn - 8))) * 16384 + (size_t)tid * 64;
      __bf16* gw = (__bf16*)gf;
#pragma unroll
      for (int mi = 0; mi < 4; ++mi) {
        bf16x8 p0, p1;
#pragma unroll
        for (int ni = 0; ni < 4; ++ni)
#pragma unroll
          for (int j = 0; j < 4; ++j) {
            const int gcol = brow0 + wc + ni * 16 + fcol;
            const float v = acc[mi][ni][j] + bias[gcol];
            const int idx = ni * 4 + j;
            if (idx < 8) p0[idx] = (__bf16)v; else p1[idx - 8] = (__bf16)v;
          }
        *(bf16x8*)(gw + foff + mi * 16) = p0;
        *(bf16x8*)(gw + foff + mi * 16 + 8) = p1;
      }
    }
  } else if (EPI == 1) {
    // prefetch z/g fragments first (overlaps with stage_ht latency)
    const size_t foff = ((size_t)(tm * 4 + tn)) * 16384 + (size_t)tid * 64;
    bf16x8 zr[4][2], gr[4][2];
#pragma unroll
    for (int mi = 0; mi < 4; ++mi) {
      zr[mi][0] = *(const bf16x8*)(zf + foff + mi * 16);
      zr[mi][1] = *(const bf16x8*)(zf + foff + mi * 16 + 8);
      gr[mi][0] = *(const bf16x8*)(gf + foff + mi * 16);
      gr[mi][1] = *(const bf16x8*)(gf + foff + mi * 16 + 8);
    }
    if (!L0) stage_ht(haux + arow0 * 512 + tn * 128, smem, w, lane);
    const bool has_last = (o_f != nullptr) && ((tm & 7) == 7);
#pragma unroll
    for (int mi = 0; mi < 4; ++mi) {
#pragma unroll
      for (int ni = 0; ni < 4; ++ni)
#pragma unroll
        for (int j = 0; j < 4; ++j) {
          const int rloc = (int)arow0 + wr + mi * 16 + frow + j;
          const int gcol = brow0 + wc + ni * 16 + fcol;
          const int idx = ni * 4 + j;
          const float zv = (float)(idx < 8 ? zr[mi][0][idx] : zr[mi][1][idx - 8]);
          const float gp = (float)(idx < 8 ? gr[mi][0][idx] : gr[mi][1][idx - 8]);
          const float gv = tanh_fast(gp + acc[mi][ni][j]);
          const float h = L0 ? h0f[bb0 * 1536 + gcol]
                             : (float)smem[(wr + mi * 16 + frow + j) * 128 + wc + ni * 16 + fcol];
          const float hv = zv * h + (1.f - zv) * gv;
          o_h[(size_t)rloc * 512 + gcol] = (__bf16)hv;
          if (has_last && ((rloc & 1023) == 1023))
            o_f[(size_t)bb0 * 1536 + gcol] = (float)(__bf16)hv;
        }
    }
  } else {
#pragma unroll
    for (int mi = 0; mi < 4; ++mi)
#pragma unroll
      for (int ni = 0; ni < 4; ++ni)
#pragma unroll
        for (int j = 0; j < 4; ++j) {
          const int rloc = (int)arow0 + wr + mi * 16 + frow + j;
          const int gcol = brow0 + wc + ni * 16 + fcol;
          o_f[(size_t)rloc * 512 + gcol] = acc[mi][ni][j] + bias[gcol];
        }
  }
}

// ---- prep kernels (unchanged, passing) ----

__global__ void prep_pack(const float* __restrict__ Wzx, const float* __restrict__ Wzh,
                          const float* __restrict__ Wrx, const float* __restrict__ Wrh,
                          const float* __restrict__ Wgx, const float* __restrict__ Wgh,
                          const float* __restrict__ Wout,
                          __bf16* __restrict__ W1t, __bf16* __restrict__ Wght,
                          __bf16* __restrict__ Woutt)
{
  const int slot = blockIdx.z;
  const float* srcA;
  const float* srcB = nullptr;
  __bf16* dst;
  if (slot < 9) {
    const int l = slot / 3, g = slot % 3;
    srcA = (g == 0 ? Wzx : g == 1 ? Wrx : Wgx) + (size_t)l * 512 * 512;
    if (l > 0 && g < 2) srcB = (g == 0 ? Wzh : Wrh) + (size_t)l * 512 * 512;
    dst = W1t + (size_t)l * 1536 * 512 + (size_t)g * 512 * 512;
  } else if (slot < 12) {
    const int l = slot - 9;
    srcA = Wgh + (size_t)l * 512 * 512;
    dst = Wght + (size_t)l * 512 * 512;
  } else {
    srcA = Wout;
    dst = Woutt;
  }
  __shared__ float tile[32][33];
  const int k0 = blockIdx.x * 32;
  const int n0 = blockIdx.y * 32;
  const int tx = threadIdx.x;
  const int ty = threadIdx.y;
  for (int i = ty; i < 32; i += 8) {
    float v = srcA[(size_t)(k0 + i) * 512 + n0 + tx];
    if (srcB) v += srcB[(size_t)(k0 + i) * 512 + n0 + tx];
    tile[i][tx] = v;
  }
  __syncthreads();
  for (int i = ty; i < 32; i += 8)
    dst[(size_t)(n0 + i) * 512 + k0 + tx] = (__bf16)tile[tx][i];
}

__global__ void cterm_kernel(const float* __restrict__ hidden,
                             const float* __restrict__ Wzh,
                             const float* __restrict__ Wrh,
                             float* __restrict__ Cterm)
{
  const int idx = blockIdx.x * blockDim.x + threadIdx.x;
  const int b = idx >> 10;
  const int n = idx & 1023;
  const float* W = (n < 512 ? Wzh : Wrh);
  const int nn = n & 511;
  const float* h0 = hidden + (size_t)b * 1536;
  float acc = 0.f;
  for (int k = 0; k < 512; ++k) acc += h0[k] * W[(size_t)k * 512 + nn];
  Cterm[idx] = acc;
}

__global__ void small_prep(const float* __restrict__ bzx, const float* __restrict__ brx,
                           const float* __restrict__ bgx, const float* __restrict__ hidden,
                           float* __restrict__ bias1, float* __restrict__ out_hidden)
{
  const int idx = blockIdx.x * blockDim.x + threadIdx.x;
  if (idx < 3 * 1536) {
    const int l = idx / 1536, j = idx % 1536;
    const float* src = (j < 512 ? bzx : j < 1024 ? brx : bgx);
    bias1[idx] = src[l * 512 + (j & 511)];
  }
  const int hidx = idx - 3 * 1536;
  if (hidx >= 0 && hidx < 64 * 512) {
    const int b = hidx >> 9, n = hidx & 511;
    out_hidden[(size_t)b * 1536 + n] = hidden[(size_t)b * 1536 + n];
  }
}

__global__ void convert_x(const float* __restrict__ src, __bf16* __restrict__ dst, long n)
{
  const long i = ((long)blockIdx.x * blockDim.x + threadIdx.x) * 8;
  if (i >= n) return;
  const f32x4 a = *(const f32x4*)(src + i);
  const f32x4 b = *(const f32x4*)(src + i + 4);
  bf16x8 o;
  o[0] = (__bf16)a[0]; o[1] = (__bf16)a[1]; o[2] = (__bf16)a[2]; o[3] = (__bf16)a[3];
  o[4] = (__bf16)b[0]; o[5] = (__bf16)b[1]; o[6] = (__bf16)b[2]; o[7] = (__bf16)b[3];
  *(bf16x8*)(dst + i) = o;
}

extern "C" void kernel_launch(void* const* d_in, const int* in_sizes, int n_in,
                              void* d_out, int out_size, void* d_ws, size_t ws_size,
                              hipStream_t stream) {
  const float* input  = (const float*)d_in[0];
  const float* hidden = (const float*)d_in[1];
  const float* Wzx = (const float*)d_in[2];
  const float* bzx = (const float*)d_in[3];
  const float* Wzh = (const float*)d_in[4];
  const float* Wrx = (const float*)d_in[5];
  const float* brx = (const float*)d_in[6];
  const float* Wrh = (const float*)d_in[7];
  const float* Wgx = (const float*)d_in[8];
  const float* bgx = (const float*)d_in[9];
  const float* Wgh = (const float*)d_in[10];
  const float* Wout = (const float*)d_in[11];
  const float* bout = (const float*)d_in[12];

  float* out = (float*)d_out;
  float* out_hidden = out + HID_OFF;

  char* ws = (char*)d_ws;
  size_t off = 0;
  auto carve = [&](size_t bytes) -> void* {
    off = (off + 255) & ~(size_t)255;
    void* p = ws + off;
    off += bytes;
    return p;
  };

  __bf16* W1t   = (__bf16*)carve(3ull * 1536 * 512 * 2);
  __bf16* Wght  = (__bf16*)carve(3ull * 512 * 512 * 2);
  __bf16* Woutt = (__bf16*)carve(512ull * 512 * 2);
  float*  bias1 = (float*) carve(3ull * 1536 * 4);
  float*  Cterm = (float*) carve(64ull * 1024 * 4);
  const size_t fixed_end = off;

  long chunk_rows = NROWS;
  int C = 1;
  while (C < 32) {
    const size_t need = ((fixed_end + 255) & ~(size_t)255) +
                        5ull * (size_t)chunk_rows * 512 * 2 + 5 * 256;
    if (need <= ws_size) break;
    C *= 2;
    chunk_rows /= 2;
  }
  __bf16* bufA  = (__bf16*)carve((size_t)chunk_rows * 512 * 2);
  __bf16* bufB  = (__bf16*)carve((size_t)chunk_rows * 512 * 2);
  __bf16* zfrag = (__bf16*)carve((size_t)chunk_rows * 512 * 2);
  __bf16* rhb   = (__bf16*)carve((size_t)chunk_rows * 512 * 2);
  __bf16* gfrag = (__bf16*)carve((size_t)chunk_rows * 512 * 2);

  small_prep<<<(3 * 1536 + 64 * 512 + 255) / 256, 256, 0, stream>>>(
      bzx, brx, bgx, hidden, bias1, out_hidden);
  dim3 tp_grid(16, 16, 13), tp_blk(32, 8);
  prep_pack<<<tp_grid, tp_blk, 0, stream>>>(Wzx, Wzh, Wrx, Wrh, Wgx, Wgh, Wout,
                                            W1t, Wght, Woutt);
  cterm_kernel<<<65536 / 256, 256, 0, stream>>>(hidden, Wzh, Wrh, Cterm);

  for (int c = 0; c < C; ++c) {
    const long row_off = (long)c * chunk_rows;
    const long nelem = chunk_rows * 512;
    const int mt = (int)(chunk_rows / 128);

    convert_x<<<(int)((nelem / 8 + 255) / 256), 256, 0, stream>>>(
        input + (size_t)row_off * 512, bufA, nelem);

    // layer 0
    gemm13<0, true><<<mt * 12, 256, 0, stream>>>(
        bufA, W1t, 12, (int)row_off, bias1, Cterm, hidden, nullptr,
        zfrag, gfrag, rhb, nullptr, nullptr);
    gemm13<1, true><<<mt * 4, 256, 0, stream>>>(
        rhb, Wght, 4, (int)row_off, nullptr, nullptr, hidden, nullptr,
        zfrag, gfrag, nullptr, bufB, out_hidden + 512);

    // layer 1 (x == h == bufB)
    gemm13<0, false><<<mt * 12, 256, 0, stream>>>(
        bufB, W1t + 1536 * 512, 12, (int)row_off, bias1 + 1536, nullptr, nullptr, bufB,
        zfrag, gfrag, rhb, nullptr, nullptr);
    gemm13<1, false><<<mt * 4, 256, 0, stream>>>(
        rhb, Wght + 512 * 512, 4, (int)row_off, nullptr, nullptr, nullptr, bufB,
        zfrag, gfrag, nullptr, bufA, out_hidden + 1024);

    // layer 2 (x == h == bufA)
    gemm13<0, false><<<mt * 12, 256, 0, stream>>>(
        bufA, W1t + 2 * 1536 * 512, 12, (int)row_off, bias1 + 3072, nullptr, nullptr, bufA,
        zfrag, gfrag, rhb, nullptr, nullptr);
    gemm13<1, false><<<mt * 4, 256, 0, stream>>>(
        rhb, Wght + 2 * 512 * 512, 4, (int)row_off, nullptr, nullptr, nullptr, bufA,
        zfrag, gfrag, nullptr, bufB, nullptr);

    // output projection
    gemm13<2, false><<<mt * 4, 256, 0, stream>>>(
        bufB, Woutt, 4, (int)row_off, bout, nullptr, nullptr, nullptr,
        nullptr, nullptr, nullptr, nullptr, out + (size_t)row_off * 512);
  }
}

// Round 14
// 1312.162 us; speedup vs baseline: 1.3702x; 1.3702x over previous
//
#include <hip/hip_runtime.h>

// MultilayerGRU — reference's indexing bug makes every (b,t) independent:
// 7 chained GEMMs over a 65536x512 activation matrix.
// Round 14: HALVE THE STAGING WALL. All structures converge to ~15.5 B/cyc/CU
// global_load_lds ingest; staged bytes ∝ (1/BM+1/BN). 256x256 tile halves it
// (7.3GB -> 3.7GB pipeline-wide). Schedule = R9's PROVEN depth-2 / 3-slot /
// counted-vmcnt(2) / one-barrier-per-step, at 1024 thr / 16 waves (4/SIMD),
// launch_bounds(1024,1), VGPR ~110 (acc 64 + frags 32). Gates additionally
// relay h in fragment order -> update kernels have no LDS epilogue at all.

typedef __attribute__((ext_vector_type(4))) float f32x4;
typedef __attribute__((ext_vector_type(8))) __bf16 bf16x8;

#define NROWS 65536          // B*S
#define HID_OFF 33554432ull  // B*S*O floats, start of hidden_out in d_out

__device__ __forceinline__ void gload16(const void* g, void* l) {
  __builtin_amdgcn_global_load_lds((const __attribute__((address_space(1))) void*)g,
                                   (__attribute__((address_space(3))) void*)l,
                                   16, 0, 0);
}
__device__ __forceinline__ float sigmoidf_(float x) { return 1.f / (1.f + __expf(-x)); }
__device__ __forceinline__ float tanh_fast(float x) {
  const float e = __expf(2.f * x);
  return 1.f - 2.f / (e + 1.f);
}

// Stage one 256x32 bf16 tile (16KB) with 1024 threads (1 gload16 each).
// LDS[row][slot] holds global chunk (slot ^ ((row>>1)&3)) -> 2-way-free reads.
__device__ __forceinline__ void stage256(const __bf16* __restrict__ src, int k0,
                                         __bf16* lds, int w, int lane) {
  const int s = w * 64 + lane;          // chunk 0..1023
  const int row = s >> 2;               // 0..255
  const int cc = ((s & 3) ^ (row >> 1)) & 3;
  gload16(src + (size_t)row * 512 + k0 + cc * 8, lds + (w * 64) * 8);
}

// Swizzled fragment read from a [R][32] tile: slot = (lane>>4) ^ ((row>>1)&3).
__device__ __forceinline__ bf16x8 frag32(const __bf16* t, int row, int lane) {
  const int c = (((lane >> 4) ^ (row >> 1)) & 3);
  return *(const bf16x8*)(t + row * 32 + c * 8);
}

// Stage a 256x128 bf16 tile of haux (512-col row-major) into 64KB LDS.
__device__ __forceinline__ void stage_ht256(const __bf16* __restrict__ src,
                                            __bf16* Ht, int w, int lane) {
#pragma unroll
  for (int i = 0; i < 4; ++i) {
    const int s0 = i * 1024 + w * 64;   // 16B chunks, 16 per row
    const int s = s0 + lane;
    const int row = s >> 4, cc = s & 15;
    gload16(src + (size_t)row * 512 + cc * 8, Ht + s0 * 8);
  }
  asm volatile("s_waitcnt vmcnt(0)");
  __builtin_amdgcn_sched_barrier(0);
  __builtin_amdgcn_s_barrier();
  __builtin_amdgcn_sched_barrier(0);
}

// EPI: 0 = gates (N=1536: z|r|gpart), 1 = update (N=512), 2 = out (N=512)
template<int EPI, bool L0>
__global__ __launch_bounds__(1024, 1) void gemm14(
    const __bf16* __restrict__ A,     // M x 512 row-major
    const __bf16* __restrict__ Bt,    // N x 512 (pre-transposed weights)
    int tiles_n, int row_off,
    const float* __restrict__ bias,
    const float* __restrict__ cterm,  // L0 gates: 64 x 1024 fp32
    const float* __restrict__ h0f,    // L0: hidden_state base (B x 3*512)
    const __bf16* __restrict__ haux,  // L>=1 gates: h row-major
    const __bf16* __restrict__ zf,    // relay (EPI0 write / EPI1 read)
    const __bf16* __restrict__ gf,    // relay (EPI0 write / EPI1 read)
    const __bf16* __restrict__ hf,    // relay (EPI0 write / EPI1 read), L>=1
    __bf16* __restrict__ o_rh,        // EPI0: r*h row-major
    __bf16* __restrict__ o_h,         // EPI1: h row-major
    float* __restrict__ o_f)          // EPI1: hidden_out slot; EPI2: out
{
  __shared__ alignas(16) __bf16 smem[49152];   // 96KB: 3 slots x (A16K + B16K)
  __bf16* const A0 = smem;
  __bf16* const B0 = smem + 8192;
  __bf16* const A1 = smem + 16384;
  __bf16* const B1 = smem + 24576;
  __bf16* const A2 = smem + 32768;
  __bf16* const B2 = smem + 40960;

  const int tid = threadIdx.x, lane = tid & 63, w = tid >> 6;
  const int wm = w >> 2, wn = w & 3;   // wave tile: rows wm*64, cols wn*64

  // T1: bijective XCD swizzle (m204)
  int bid = blockIdx.x;
  {
    const int nwg = gridDim.x;
    const int q = nwg >> 3, r = nwg & 7;
    const int x = bid & 7, rest = bid >> 3;
    bid = (x < r ? x * (q + 1) : r * (q + 1) + (x - r) * q) + rest;
  }
  const int tm = bid / tiles_n;
  const int tn = bid - tm * tiles_n;
  const size_t arow0 = (size_t)tm * 256;
  const int brow0 = tn * 256;
  const __bf16* const Ab = A + arow0 * 512;
  const __bf16* const Bb = Bt + (size_t)brow0 * 512;

  f32x4 acc[4][4];
  const f32x4 zz = {0.f, 0.f, 0.f, 0.f};
#pragma unroll
  for (int i = 0; i < 4; ++i)
#pragma unroll
    for (int j = 0; j < 4; ++j) acc[i][j] = zz;

  // one k-step (R9 schedule): stage tile t+2 (1 A-load + 1 B-load per thread),
  // read current frags, MFMA, counted vmcnt(2) (tile t+1 landed), barrier.
  auto stepf = [&](int kst, const __bf16* cA, const __bf16* cB,
                   __bf16* nA, __bf16* nB, int vm) {
    if (nA) {
      stage256(Ab, kst, nA, w, lane);
      stage256(Bb, kst, nB, w, lane);
    }
    bf16x8 af[4], bf_[4];
#pragma unroll
    for (int i = 0; i < 4; ++i) {
      af[i]  = frag32(cA, wm * 64 + i * 16 + (lane & 15), lane);
      bf_[i] = frag32(cB, wn * 64 + i * 16 + (lane & 15), lane);
    }
#pragma unroll
    for (int mi = 0; mi < 4; ++mi)
#pragma unroll
      for (int ni = 0; ni < 4; ++ni)
        acc[mi][ni] = __builtin_amdgcn_mfma_f32_16x16x32_bf16(af[mi], bf_[ni], acc[mi][ni], 0, 0, 0);
    if (vm == 2) {
      asm volatile("s_waitcnt vmcnt(2)");
      __builtin_amdgcn_sched_barrier(0);
    } else if (vm == 0) {
      asm volatile("s_waitcnt vmcnt(0)");
      __builtin_amdgcn_sched_barrier(0);
    }
    __builtin_amdgcn_s_barrier();
    __builtin_amdgcn_sched_barrier(0);
  };

  // prologue: stage tiles 0,1 (4 loads/thread total); vmcnt(2) -> tile0 landed.
  stage256(Ab, 0, A0, w, lane);
  stage256(Bb, 0, B0, w, lane);
  stage256(Ab, 32, A1, w, lane);
  stage256(Bb, 32, B1, w, lane);
  asm volatile("s_waitcnt vmcnt(2)");
  __builtin_amdgcn_sched_barrier(0);
  __builtin_amdgcn_s_barrier();
  __builtin_amdgcn_sched_barrier(0);

  // steps 0..11 (stage tiles 2..13); slot rotation period 3
#pragma unroll 1
  for (int it = 0; it < 4; ++it) {
    const int kb = it * 96;
    stepf(kb + 64,  A0, B0, A2, B2, 2);   // t: cur slot0, stage slot2
    stepf(kb + 96,  A1, B1, A0, B0, 2);   // t+1
    stepf(kb + 128, A2, B2, A1, B1, 2);   // t+2
  }
  // tail: t=12 stage14, t=13 stage15, t=14 drain, t=15 none
  stepf(14 * 32, A0, B0, A2, B2, 2);
  stepf(15 * 32, A1, B1, A0, B0, 2);
  stepf(0,       A2, B2, nullptr, nullptr, 0);
  stepf(0,       A0, B0, nullptr, nullptr, -1);
  __builtin_amdgcn_s_barrier();   // k-loop smem free before epilogue reuse

  // ---------------- epilogues ----------------
  const int fcol = lane & 15;
  const int frow = (lane >> 4) * 4;
  const int bb0 = (row_off + (int)arow0) >> 10;  // batch idx, uniform per tile

  if (EPI == 0) {
    if (tn < 2) {
      // z quadrant -> sigmoid, fragment-order relay
      const size_t foff = ((size_t)(tm * 2 + tn)) * 65536 + (size_t)tid * 64;
      __bf16* zw = (__bf16*)zf;
#pragma unroll
      for (int mi = 0; mi < 4; ++mi) {
        bf16x8 p0, p1;
#pragma unroll
        for (int ni = 0; ni < 4; ++ni)
#pragma unroll
          for (int j = 0; j < 4; ++j) {
            const int gcol = brow0 + wn * 64 + ni * 16 + fcol;
            float c = acc[mi][ni][j] + bias[gcol];
            if (L0) c += cterm[bb0 * 1024 + gcol];
            const float v = sigmoidf_(c);
            const int idx = ni * 4 + j;
            if (idx < 8) p0[idx] = (__bf16)v; else p1[idx - 8] = (__bf16)v;
          }
        *(bf16x8*)(zw + foff + mi * 16) = p0;
        *(bf16x8*)(zw + foff + mi * 16 + 8) = p1;
      }
    } else if (tn < 4) {
      // r quadrant -> r*h row-major + h relay (L>=1 h via 2-pass LDS tile)
      const int u = tn - 2;
      const size_t foffh = ((size_t)(tm * 2 + u)) * 65536 + (size_t)tid * 64;
      __bf16* hw = (__bf16*)hf;
      if (L0) {
#pragma unroll
        for (int mi = 0; mi < 4; ++mi)
#pragma unroll
          for (int ni = 0; ni < 4; ++ni)
#pragma unroll
            for (int j = 0; j < 4; ++j) {
              const int rloc = (int)arow0 + wm * 64 + mi * 16 + frow + j;
              const int gcol = brow0 + wn * 64 + ni * 16 + fcol;
              const int nn = gcol - 512;
              float c = acc[mi][ni][j] + bias[gcol] + cterm[bb0 * 1024 + gcol];
              const float rv = sigmoidf_(c);
              const float h = h0f[bb0 * 1536 + nn];
              o_rh[(size_t)rloc * 512 + nn] = (__bf16)(rv * h);
            }
      } else {
#pragma unroll 1
        for (int p = 0; p < 2; ++p) {
          __syncthreads();   // prior readers done before overwriting smem
          stage_ht256(haux + arow0 * 512 + u * 256 + p * 128, smem, w, lane);
          if (((w >> 1) & 1) == p) {   // waves whose cols lie in this half
#pragma unroll
            for (int mi = 0; mi < 4; ++mi) {
              bf16x8 h0v, h1v;
#pragma unroll
              for (int ni = 0; ni < 4; ++ni)
#pragma unroll
                for (int j = 0; j < 4; ++j) {
                  const int rloc = (int)arow0 + wm * 64 + mi * 16 + frow + j;
                  const int gcol = brow0 + wn * 64 + ni * 16 + fcol;
                  const int nn = gcol - 512;
                  float c = acc[mi][ni][j] + bias[gcol];
                  const float rv = sigmoidf_(c);
                  const int lr = wm * 64 + mi * 16 + frow + j;
                  const int lc = (w & 1) * 64 + ni * 16 + fcol;
                  const __bf16 hb = smem[lr * 128 + lc];
                  o_rh[(size_t)rloc * 512 + nn] = (__bf16)(rv * (float)hb);
                  const int idx = ni * 4 + j;
                  if (idx < 8) h0v[idx] = hb; else h1v[idx - 8] = hb;
                }
              *(bf16x8*)(hw + foffh + mi * 16) = h0v;
              *(bf16x8*)(hw + foffh + mi * 16 + 8) = h1v;
            }
          }
        }
      }
    } else {
      // g-partial quadrant -> fragment-order relay (raw + bias)
      const size_t foff = ((size_t)(tm * 2 + (tn - 4))) * 65536 + (size_t)tid * 64;
      __bf16* gw = (__bf16*)gf;
#pragma unroll
      for (int mi = 0; mi < 4; ++mi) {
        bf16x8 p0, p1;
#pragma unroll
        for (int ni = 0; ni < 4; ++ni)
#pragma unroll
          for (int j = 0; j < 4; ++j) {
            const int gcol = brow0 + wn * 64 + ni * 16 + fcol;
            const float v = acc[mi][ni][j] + bias[gcol];
            const int idx = ni * 4 + j;
            if (idx < 8) p0[idx] = (__bf16)v; else p1[idx - 8] = (__bf16)v;
          }
        *(bf16x8*)(gw + foff + mi * 16) = p0;
        *(bf16x8*)(gw + foff + mi * 16 + 8) = p1;
      }
    }
  } else if (EPI == 1) {
    const size_t foff = ((size_t)(tm * 2 + tn)) * 65536 + (size_t)tid * 64;
    const bool has_last = (o_f != nullptr) && ((tm & 3) == 3);
#pragma unroll
    for (int mi = 0; mi < 4; ++mi) {
      const bf16x8 z0 = *(const bf16x8*)(zf + foff + mi * 16);
      const bf16x8 z1 = *(const bf16x8*)(zf + foff + mi * 16 + 8);
      const bf16x8 g0 = *(const bf16x8*)(gf + foff + mi * 16);
      const bf16x8 g1 = *(const bf16x8*)(gf + foff + mi * 16 + 8);
      bf16x8 h0v, h1v;
      if (!L0) {
        h0v = *(const bf16x8*)(hf + foff + mi * 16);
        h1v = *(const bf16x8*)(hf + foff + mi * 16 + 8);
      }
#pragma unroll
      for (int ni = 0; ni < 4; ++ni)
#pragma unroll
        for (int j = 0; j < 4; ++j) {
          const int rloc = (int)arow0 + wm * 64 + mi * 16 + frow + j;
          const int gcol = brow0 + wn * 64 + ni * 16 + fcol;
          const int idx = ni * 4 + j;
          const float zv = (float)(idx < 8 ? z0[idx] : z1[idx - 8]);
          const float gp = (float)(idx < 8 ? g0[idx] : g1[idx - 8]);
          const float gv = tanh_fast(gp + acc[mi][ni][j]);
          const float h = L0 ? h0f[bb0 * 1536 + gcol]
                             : (float)(idx < 8 ? h0v[idx] : h1v[idx - 8]);
          const float hv = zv * h + (1.f - zv) * gv;
          o_h[(size_t)rloc * 512 + gcol] = (__bf16)hv;
          if (has_last && ((rloc & 1023) == 1023))
            o_f[(size_t)bb0 * 1536 + gcol] = (float)(__bf16)hv;
        }
    }
  } else {
#pragma unroll
    for (int mi = 0; mi < 4; ++mi)
#pragma unroll
      for (int ni = 0; ni < 4; ++ni)
#pragma unroll
        for (int j = 0; j < 4; ++j) {
          const int rloc = (int)arow0 + wm * 64 + mi * 16 + frow + j;
          const int gcol = brow0 + wn * 64 + ni * 16 + fcol;
          o_f[(size_t)rloc * 512 + gcol] = acc[mi][ni][j] + bias[gcol];
        }
  }
}

// ---- prep kernels (unchanged, passing) ----

__global__ void prep_pack(const float* __restrict__ Wzx, const float* __restrict__ Wzh,
                          const float* __restrict__ Wrx, const float* __restrict__ Wrh,
                          const float* __restrict__ Wgx, const float* __restrict__ Wgh,
                          const float* __restrict__ Wout,
                          __bf16* __restrict__ W1t, __bf16* __restrict__ Wght,
                          __bf16* __restrict__ Woutt)
{
  const int slot = blockIdx.z;
  const float* srcA;
  const float* srcB = nullptr;
  __bf16* dst;
  if (slot < 9) {
    const int l = slot / 3, g = slot % 3;
    srcA = (g == 0 ? Wzx : g == 1 ? Wrx : Wgx) + (size_t)l * 512 * 512;
    if (l > 0 && g < 2) srcB = (g == 0 ? Wzh : Wrh) + (size_t)l * 512 * 512;
    dst = W1t + (size_t)l * 1536 * 512 + (size_t)g * 512 * 512;
  } else if (slot < 12) {
    const int l = slot - 9;
    srcA = Wgh + (size_t)l * 512 * 512;
    dst = Wght + (size_t)l * 512 * 512;
  } else {
    srcA = Wout;
    dst = Woutt;
  }
  __shared__ float tile[32][33];
  const int k0 = blockIdx.x * 32;
  const int n0 = blockIdx.y * 32;
  const int tx = threadIdx.x;
  const int ty = threadIdx.y;
  for (int i = ty; i < 32; i += 8) {
    float v = srcA[(size_t)(k0 + i) * 512 + n0 + tx];
    if (srcB) v += srcB[(size_t)(k0 + i) * 512 + n0 + tx];
    tile[i][tx] = v;
  }
  __syncthreads();
  for (int i = ty; i < 32; i += 8)
    dst[(size_t)(n0 + i) * 512 + k0 + tx] = (__bf16)tile[tx][i];
}

__global__ void cterm_kernel(const float* __restrict__ hidden,
                             const float* __restrict__ Wzh,
                             const float* __restrict__ Wrh,
                             float* __restrict__ Cterm)
{
  const int idx = blockIdx.x * blockDim.x + threadIdx.x;
  const int b = idx >> 10;
  const int n = idx & 1023;
  const float* W = (n < 512 ? Wzh : Wrh);
  const int nn = n & 511;
  const float* h0 = hidden + (size_t)b * 1536;
  float acc = 0.f;
  for (int k = 0; k < 512; ++k) acc += h0[k] * W[(size_t)k * 512 + nn];
  Cterm[idx] = acc;
}

__global__ void small_prep(const float* __restrict__ bzx, const float* __restrict__ brx,
                           const float* __restrict__ bgx, const float* __restrict__ hidden,
                           float* __restrict__ bias1, float* __restrict__ out_hidden)
{
  const int idx = blockIdx.x * blockDim.x + threadIdx.x;
  if (idx < 3 * 1536) {
    const int l = idx / 1536, j = idx % 1536;
    const float* src = (j < 512 ? bzx : j < 1024 ? brx : bgx);
    bias1[idx] = src[l * 512 + (j & 511)];
  }
  const int hidx = idx - 3 * 1536;
  if (hidx >= 0 && hidx < 64 * 512) {
    const int b = hidx >> 9, n = hidx & 511;
    out_hidden[(size_t)b * 1536 + n] = hidden[(size_t)b * 1536 + n];
  }
}

__global__ void convert_x(const float* __restrict__ src, __bf16* __restrict__ dst, long n)
{
  const long i = ((long)blockIdx.x * blockDim.x + threadIdx.x) * 8;
  if (i >= n) return;
  const f32x4 a = *(const f32x4*)(src + i);
  const f32x4 b = *(const f32x4*)(src + i + 4);
  bf16x8 o;
  o[0] = (__bf16)a[0]; o[1] = (__bf16)a[1]; o[2] = (__bf16)a[2]; o[3] = (__bf16)a[3];
  o[4] = (__bf16)b[0]; o[5] = (__bf16)b[1]; o[6] = (__bf16)b[2]; o[7] = (__bf16)b[3];
  *(bf16x8*)(dst + i) = o;
}

extern "C" void kernel_launch(void* const* d_in, const int* in_sizes, int n_in,
                              void* d_out, int out_size, void* d_ws, size_t ws_size,
                              hipStream_t stream) {
  const float* input  = (const float*)d_in[0];
  const float* hidden = (const float*)d_in[1];
  const float* Wzx = (const float*)d_in[2];
  const float* bzx = (const float*)d_in[3];
  const float* Wzh = (const float*)d_in[4];
  const float* Wrx = (const float*)d_in[5];
  const float* brx = (const float*)d_in[6];
  const float* Wrh = (const float*)d_in[7];
  const float* Wgx = (const float*)d_in[8];
  const float* bgx = (const float*)d_in[9];
  const float* Wgh = (const float*)d_in[10];
  const float* Wout = (const float*)d_in[11];
  const float* bout = (const float*)d_in[12];

  float* out = (float*)d_out;
  float* out_hidden = out + HID_OFF;

  char* ws = (char*)d_ws;
  size_t off = 0;
  auto carve = [&](size_t bytes) -> void* {
    off = (off + 255) & ~(size_t)255;
    void* p = ws + off;
    off += bytes;
    return p;
  };

  __bf16* W1t   = (__bf16*)carve(3ull * 1536 * 512 * 2);
  __bf16* Wght  = (__bf16*)carve(3ull * 512 * 512 * 2);
  __bf16* Woutt = (__bf16*)carve(512ull * 512 * 2);
  float*  bias1 = (float*) carve(3ull * 1536 * 4);
  float*  Cterm = (float*) carve(64ull * 1024 * 4);
  const size_t fixed_end = off;

  long chunk_rows = NROWS;
  int C = 1;
  while (C < 32) {
    const size_t need = ((fixed_end + 255) & ~(size_t)255) +
                        6ull * (size_t)chunk_rows * 512 * 2 + 6 * 256;
    if (need <= ws_size) break;
    C *= 2;
    chunk_rows /= 2;
  }
  __bf16* bufA  = (__bf16*)carve((size_t)chunk_rows * 512 * 2);
  __bf16* bufB  = (__bf16*)carve((size_t)chunk_rows * 512 * 2);
  __bf16* zfrag = (__bf16*)carve((size_t)chunk_rows * 512 * 2);
  __bf16* rhb   = (__bf16*)carve((size_t)chunk_rows * 512 * 2);
  __bf16* gfrag = (__bf16*)carve((size_t)chunk_rows * 512 * 2);
  __bf16* hfrag = (__bf16*)carve((size_t)chunk_rows * 512 * 2);

  small_prep<<<(3 * 1536 + 64 * 512 + 255) / 256, 256, 0, stream>>>(
      bzx, brx, bgx, hidden, bias1, out_hidden);
  dim3 tp_grid(16, 16, 13), tp_blk(32, 8);
  prep_pack<<<tp_grid, tp_blk, 0, stream>>>(Wzx, Wzh, Wrx, Wrh, Wgx, Wgh, Wout,
                                            W1t, Wght, Woutt);
  cterm_kernel<<<65536 / 256, 256, 0, stream>>>(hidden, Wzh, Wrh, Cterm);

  for (int c = 0; c < C; ++c) {
    const long row_off = (long)c * chunk_rows;
    const long nelem = chunk_rows * 512;
    const int mt2 = (int)(chunk_rows / 256);

    convert_x<<<(int)((nelem / 8 + 255) / 256), 256, 0, stream>>>(
        input + (size_t)row_off * 512, bufA, nelem);

    // layer 0
    gemm14<0, true><<<mt2 * 6, 1024, 0, stream>>>(
        bufA, W1t, 6, (int)row_off, bias1, Cterm, hidden, nullptr,
        zfrag, gfrag, hfrag, rhb, nullptr, nullptr);
    gemm14<1, true><<<mt2 * 2, 1024, 0, stream>>>(
        rhb, Wght, 2, (int)row_off, nullptr, nullptr, hidden, nullptr,
        zfrag, gfrag, hfrag, nullptr, bufB, out_hidden + 512);

    // layer 1 (x == h == bufB)
    gemm14<0, false><<<mt2 * 6, 1024, 0, stream>>>(
        bufB, W1t + 1536 * 512, 6, (int)row_off, bias1 + 1536, nullptr, nullptr, bufB,
        zfrag, gfrag, hfrag, rhb, nullptr, nullptr);
    gemm14<1, false><<<mt2 * 2, 1024, 0, stream>>>(
        rhb, Wght + 512 * 512, 2, (int)row_off, nullptr, nullptr, nullptr, nullptr,
        zfrag, gfrag, hfrag, nullptr, bufA, out_hidden + 1024);

    // layer 2 (x == h == bufA)
    gemm14<0, false><<<mt2 * 6, 1024, 0, stream>>>(
        bufA, W1t + 2 * 1536 * 512, 6, (int)row_off, bias1 + 3072, nullptr, nullptr, bufA,
        zfrag, gfrag, hfrag, rhb, nullptr, nullptr);
    gemm14<1, false><<<mt2 * 2, 1024, 0, stream>>>(
        rhb, Wght + 2 * 512 * 512, 2, (int)row_off, nullptr, nullptr, nullptr, nullptr,
        zfrag, gfrag, hfrag, nullptr, bufB, nullptr);

    // output projection
    gemm14<2, false><<<mt2 * 2, 1024, 0, stream>>>(
        bufB, Woutt, 2, (int)row_off, bout, nullptr, nullptr, nullptr,
        nullptr, nullptr, nullptr, nullptr, nullptr, out + (size_t)row_off * 512);
  }
}

// Round 15
// 903.796 us; speedup vs baseline: 1.9893x; 1.4518x over previous
//
#include <hip/hip_runtime.h>

// MultilayerGRU — reference's indexing bug makes every (b,t) independent:
// 7 chained GEMMs over a 65536x512 activation matrix.
// Round 15: MAX-WAVES cell of the sweep. Ingest rate tracks resident waves
// (16w->15.5 B/cyc/CU, 12w->15.7, 8w->14.2, 16-lockstep->5; m97 with big K
// reaches 41). R9 base, GEMM rebuilt as 8-wave/512-thread 128^2 blocks:
// wave = 32x64 (acc[2][4]=32 VGPR), depth-1 dbuf, 32KB LDS, conflict-free
// swizzle, launch_bounds(512,6) -> 3 blocks/CU = 24 waves/CU.

typedef __attribute__((ext_vector_type(4))) float f32x4;
typedef __attribute__((ext_vector_type(8))) __bf16 bf16x8;

#define NROWS 65536          // B*S
#define HID_OFF 33554432ull  // B*S*O floats, start of hidden_out in d_out

__device__ __forceinline__ void gload16(const void* g, void* l) {
  __builtin_amdgcn_global_load_lds((const __attribute__((address_space(1))) void*)g,
                                   (__attribute__((address_space(3))) void*)l,
                                   16, 0, 0);
}
__device__ __forceinline__ float sigmoidf_(float x) { return 1.f / (1.f + __expf(-x)); }
__device__ __forceinline__ float tanh_fast(float x) {
  const float e = __expf(2.f * x);
  return 1.f - 2.f / (e + 1.f);
}

// Stage one 128x32 bf16 tile (8KB) with 512 threads (1 gload16 each).
// LDS[row][slot] holds global chunk (slot ^ ((row>>1)&3)) -> 2-way-free reads
// (verified R9/R12: conflicts 1.36e7 -> 1.05e6).
__device__ __forceinline__ void stage32(const __bf16* __restrict__ src, int k0,
                                        __bf16* lds, int w, int lane) {
  const int s = w * 64 + lane;          // chunk 0..511
  const int row = s >> 2;               // 0..127
  const int cc = ((s & 3) ^ (row >> 1)) & 3;
  gload16(src + (size_t)row * 512 + k0 + cc * 8, lds + (w * 64) * 8);
}

// Swizzled fragment read from a [128][32] tile: slot = (lane>>4) ^ ((row>>1)&3).
__device__ __forceinline__ bf16x8 frag32(const __bf16* t, int row, int lane) {
  const int c = (((lane >> 4) ^ (row >> 1)) & 3);
  return *(const bf16x8*)(t + row * 32 + c * 8);
}

// Stage a 128x128 bf16 tile of haux (512-col row-major) into 32KB LDS (512 thr).
__device__ __forceinline__ void stage_ht(const __bf16* __restrict__ src,
                                         __bf16* Ht, int w, int lane) {
#pragma unroll
  for (int i = 0; i < 4; ++i) {
    const int s0 = i * 512 + w * 64;    // 16B chunks, 16 per row
    const int s = s0 + lane;
    const int row = s >> 4, cc = s & 15;
    gload16(src + (size_t)row * 512 + cc * 8, Ht + s0 * 8);
  }
  asm volatile("s_waitcnt vmcnt(0)");
  __builtin_amdgcn_sched_barrier(0);
  __builtin_amdgcn_s_barrier();
  __builtin_amdgcn_sched_barrier(0);
}

// EPI: 0 = gates (N=1536: z|r|gpart), 1 = update (N=512), 2 = out (N=512)
template<int EPI, bool L0>
__global__ __launch_bounds__(512, 6) void gemm15(
    const __bf16* __restrict__ A,     // M x 512 row-major
    const __bf16* __restrict__ Bt,    // N x 512 (pre-transposed weights)
    int tiles_n, int row_off,
    const float* __restrict__ bias,
    const float* __restrict__ cterm,  // L0 gates: 64 x 1024 fp32
    const float* __restrict__ h0f,    // L0: hidden_state base (B x 3*512)
    const __bf16* __restrict__ haux,  // L>=1: h row-major
    const __bf16* __restrict__ zf,    // relay (EPI0 write / EPI1 read)
    const __bf16* __restrict__ gf,    // relay (EPI0 write / EPI1 read)
    __bf16* __restrict__ o_rh,        // EPI0: r*h row-major
    __bf16* __restrict__ o_h,         // EPI1: h row-major
    float* __restrict__ o_f)          // EPI1: hidden_out slot; EPI2: out
{
  __shared__ alignas(16) __bf16 smem[16384];   // 32KB: 2 x (A 8KB + B 8KB)
  __bf16* const A0 = smem;
  __bf16* const B0 = smem + 4096;
  __bf16* const A1 = smem + 8192;
  __bf16* const B1 = smem + 12288;

  const int tid = threadIdx.x, lane = tid & 63, w = tid >> 6;
  const int rb = (w >> 1) * 32;   // wave rows: 4 x 32
  const int cb = (w & 1) * 64;    // wave cols: 2 x 64

  // T1: bijective XCD swizzle (m204)
  int bid = blockIdx.x;
  {
    const int nwg = gridDim.x;
    const int q = nwg >> 3, r = nwg & 7;
    const int x = bid & 7, rest = bid >> 3;
    bid = (x < r ? x * (q + 1) : r * (q + 1) + (x - r) * q) + rest;
  }
  const int tm = bid / tiles_n;
  const int tn = bid - tm * tiles_n;
  const size_t arow0 = (size_t)tm * 128;
  const int brow0 = tn * 128;
  const __bf16* const Ab = A + arow0 * 512;
  const __bf16* const Bb = Bt + (size_t)brow0 * 512;

  f32x4 acc[2][4];
  const f32x4 zz = {0.f, 0.f, 0.f, 0.f};
#pragma unroll
  for (int i = 0; i < 2; ++i)
#pragma unroll
    for (int j = 0; j < 4; ++j) acc[i][j] = zz;

  // depth-1 k-step (R12 schedule, proven): issue stage of tile t+1 first
  // (flies under frag reads + MFMA), compute tile t, drain, barrier.
  auto stepf = [&](int t, const __bf16* cA, const __bf16* cB,
                   __bf16* nA, __bf16* nB) {
    if (t < 15) {
      stage32(Ab, (t + 1) * 32, nA, w, lane);
      stage32(Bb, (t + 1) * 32, nB, w, lane);
    }
    bf16x8 af[2], bf4[4];
#pragma unroll
    for (int i = 0; i < 2; ++i)
      af[i] = frag32(cA, rb + i * 16 + (lane & 15), lane);
#pragma unroll
    for (int i = 0; i < 4; ++i)
      bf4[i] = frag32(cB, cb + i * 16 + (lane & 15), lane);
#pragma unroll
    for (int mi = 0; mi < 2; ++mi)
#pragma unroll
      for (int ni = 0; ni < 4; ++ni)
        acc[mi][ni] = __builtin_amdgcn_mfma_f32_16x16x32_bf16(af[mi], bf4[ni], acc[mi][ni], 0, 0, 0);
    if (t < 15) {
      asm volatile("s_waitcnt vmcnt(0)");
      __builtin_amdgcn_sched_barrier(0);
    }
    __builtin_amdgcn_s_barrier();
    __builtin_amdgcn_sched_barrier(0);
  };

  // prologue: tile 0 into slot 0
  stage32(Ab, 0, A0, w, lane);
  stage32(Bb, 0, B0, w, lane);
  asm volatile("s_waitcnt vmcnt(0)");
  __builtin_amdgcn_sched_barrier(0);
  __builtin_amdgcn_s_barrier();
  __builtin_amdgcn_sched_barrier(0);

#pragma unroll 1
  for (int t = 0; t < 16; t += 2) {
    stepf(t,     A0, B0, A1, B1);
    stepf(t + 1, A1, B1, A0, B0);
  }

  // ---------------- epilogues ----------------
  const int fcol = lane & 15;
  const int frow = (lane >> 4) * 4;
  const int bb0 = (row_off + (int)arow0) >> 10;  // batch idx, uniform per tile

  if (EPI == 0) {
    if (tn < 4) {
      // z quadrant -> sigmoid, fragment-order relay (32 vals/thread)
      const size_t foff = ((size_t)(tm * 4 + tn)) * 16384 + (size_t)tid * 32;
      __bf16* zw = (__bf16*)zf;
#pragma unroll
      for (int mi = 0; mi < 2; ++mi) {
        bf16x8 p0, p1;
#pragma unroll
        for (int ni = 0; ni < 4; ++ni)
#pragma unroll
          for (int j = 0; j < 4; ++j) {
            const int gcol = brow0 + cb + ni * 16 + fcol;
            float c = acc[mi][ni][j] + bias[gcol];
            if (L0) c += cterm[bb0 * 1024 + gcol];
            const float v = sigmoidf_(c);
            const int idx = ni * 4 + j;
            if (idx < 8) p0[idx] = (__bf16)v; else p1[idx - 8] = (__bf16)v;
          }
        *(bf16x8*)(zw + foff + mi * 16) = p0;
        *(bf16x8*)(zw + foff + mi * 16 + 8) = p1;
      }
    } else if (tn < 8) {
      // r quadrant -> r*h row-major (h LDS-tiled for L>=1)
      if (!L0) stage_ht(haux + arow0 * 512 + (tn - 4) * 128, smem, w, lane);
#pragma unroll
      for (int mi = 0; mi < 2; ++mi)
#pragma unroll
        for (int ni = 0; ni < 4; ++ni)
#pragma unroll
          for (int j = 0; j < 4; ++j) {
            const int rloc = (int)arow0 + rb + mi * 16 + frow + j;
            const int gcol = brow0 + cb + ni * 16 + fcol;
            const int nn = gcol - 512;
            float c = acc[mi][ni][j] + bias[gcol];
            if (L0) c += cterm[bb0 * 1024 + gcol];
            const float rv = sigmoidf_(c);
            const float h = L0 ? h0f[bb0 * 1536 + nn]
                               : (float)smem[(rb + mi * 16 + frow + j) * 128 + cb + ni * 16 + fcol];
            o_rh[(size_t)rloc * 512 + nn] = (__bf16)(rv * h);
          }
    } else {
      // g-partial quadrant -> fragment-order relay (raw + bias)
      const size_t foff = ((size_t)(tm * 4 + (tn - 8))) * 16384 + (size_t)tid * 32;
      __bf16* gw = (__bf16*)gf;
#pragma unroll
      for (int mi = 0; mi < 2; ++mi) {
        bf16x8 p0, p1;
#pragma unroll
        for (int ni = 0; ni < 4; ++ni)
#pragma unroll
          for (int j = 0; j < 4; ++j) {
            const int gcol = brow0 + cb + ni * 16 + fcol;
            const float v = acc[mi][ni][j] + bias[gcol];
            const int idx = ni * 4 + j;
            if (idx < 8) p0[idx] = (__bf16)v; else p1[idx - 8] = (__bf16)v;
          }
        *(bf16x8*)(gw + foff + mi * 16) = p0;
        *(bf16x8*)(gw + foff + mi * 16 + 8) = p1;
      }
    }
  } else if (EPI == 1) {
    // prefetch z/g fragments first (overlaps with stage_ht latency)
    const size_t foff = ((size_t)(tm * 4 + tn)) * 16384 + (size_t)tid * 32;
    bf16x8 zr[2][2], gr[2][2];
#pragma unroll
    for (int mi = 0; mi < 2; ++mi) {
      zr[mi][0] = *(const bf16x8*)(zf + foff + mi * 16);
      zr[mi][1] = *(const bf16x8*)(zf + foff + mi * 16 + 8);
      gr[mi][0] = *(const bf16x8*)(gf + foff + mi * 16);
      gr[mi][1] = *(const bf16x8*)(gf + foff + mi * 16 + 8);
    }
    if (!L0) stage_ht(haux + arow0 * 512 + tn * 128, smem, w, lane);
    const bool has_last = (o_f != nullptr) && ((tm & 7) == 7);
#pragma unroll
    for (int mi = 0; mi < 2; ++mi) {
#pragma unroll
      for (int ni = 0; ni < 4; ++ni)
#pragma unroll
        for (int j = 0; j < 4; ++j) {
          const int rloc = (int)arow0 + rb + mi * 16 + frow + j;
          const int gcol = brow0 + cb + ni * 16 + fcol;
          const int idx = ni * 4 + j;
          const float zv = (float)(idx < 8 ? zr[mi][0][idx] : zr[mi][1][idx - 8]);
          const float gp = (float)(idx < 8 ? gr[mi][0][idx] : gr[mi][1][idx - 8]);
          const float gv = tanh_fast(gp + acc[mi][ni][j]);
          const float h = L0 ? h0f[bb0 * 1536 + gcol]
                             : (float)smem[(rb + mi * 16 + frow + j) * 128 + cb + ni * 16 + fcol];
          const float hv = zv * h + (1.f - zv) * gv;
          o_h[(size_t)rloc * 512 + gcol] = (__bf16)hv;
          if (has_last && ((rloc & 1023) == 1023))
            o_f[(size_t)bb0 * 1536 + gcol] = (float)(__bf16)hv;
        }
    }
  } else {
#pragma unroll
    for (int mi = 0; mi < 2; ++mi)
#pragma unroll
      for (int ni = 0; ni < 4; ++ni)
#pragma unroll
        for (int j = 0; j < 4; ++j) {
          const int rloc = (int)arow0 + rb + mi * 16 + frow + j;
          const int gcol = brow0 + cb + ni * 16 + fcol;
          o_f[(size_t)rloc * 512 + gcol] = acc[mi][ni][j] + bias[gcol];
        }
  }
}

// ---- prep kernels (unchanged, passing) ----

__global__ void prep_pack(const float* __restrict__ Wzx, const float* __restrict__ Wzh,
                          const float* __restrict__ Wrx, const float* __restrict__ Wrh,
                          const float* __restrict__ Wgx, const float* __restrict__ Wgh,
                          const float* __restrict__ Wout,
                          __bf16* __restrict__ W1t, __bf16* __restrict__ Wght,
                          __bf16* __restrict__ Woutt)
{
  const int slot = blockIdx.z;
  const float* srcA;
  const float* srcB = nullptr;
  __bf16* dst;
  if (slot < 9) {
    const int l = slot / 3, g = slot % 3;
    srcA = (g == 0 ? Wzx : g == 1 ? Wrx : Wgx) + (size_t)l * 512 * 512;
    if (l > 0 && g < 2) srcB = (g == 0 ? Wzh : Wrh) + (size_t)l * 512 * 512;
    dst = W1t + (size_t)l * 1536 * 512 + (size_t)g * 512 * 512;
  } else if (slot < 12) {
    const int l = slot - 9;
    srcA = Wgh + (size_t)l * 512 * 512;
    dst = Wght + (size_t)l * 512 * 512;
  } else {
    srcA = Wout;
    dst = Woutt;
  }
  __shared__ float tile[32][33];
  const int k0 = blockIdx.x * 32;
  const int n0 = blockIdx.y * 32;
  const int tx = threadIdx.x;
  const int ty = threadIdx.y;
  for (int i = ty; i < 32; i += 8) {
    float v = srcA[(size_t)(k0 + i) * 512 + n0 + tx];
    if (srcB) v += srcB[(size_t)(k0 + i) * 512 + n0 + tx];
    tile[i][tx] = v;
  }
  __syncthreads();
  for (int i = ty; i < 32; i += 8)
    dst[(size_t)(n0 + i) * 512 + k0 + tx] = (__bf16)tile[tx][i];
}

__global__ void cterm_kernel(const float* __restrict__ hidden,
                             const float* __restrict__ Wzh,
                             const float* __restrict__ Wrh,
                             float* __restrict__ Cterm)
{
  const int idx = blockIdx.x * blockDim.x + threadIdx.x;
  const int b = idx >> 10;
  const int n = idx & 1023;
  const float* W = (n < 512 ? Wzh : Wrh);
  const int nn = n & 511;
  const float* h0 = hidden + (size_t)b * 1536;
  float acc = 0.f;
  for (int k = 0; k < 512; ++k) acc += h0[k] * W[(size_t)k * 512 + nn];
  Cterm[idx] = acc;
}

__global__ void small_prep(const float* __restrict__ bzx, const float* __restrict__ brx,
                           const float* __restrict__ bgx, const float* __restrict__ hidden,
                           float* __restrict__ bias1, float* __restrict__ out_hidden)
{
  const int idx = blockIdx.x * blockDim.x + threadIdx.x;
  if (idx < 3 * 1536) {
    const int l = idx / 1536, j = idx % 1536;
    const float* src = (j < 512 ? bzx : j < 1024 ? brx : bgx);
    bias1[idx] = src[l * 512 + (j & 511)];
  }
  const int hidx = idx - 3 * 1536;
  if (hidx >= 0 && hidx < 64 * 512) {
    const int b = hidx >> 9, n = hidx & 511;
    out_hidden[(size_t)b * 1536 + n] = hidden[(size_t)b * 1536 + n];
  }
}

__global__ void convert_x(const float* __restrict__ src, __bf16* __restrict__ dst, long n)
{
  const long i = ((long)blockIdx.x * blockDim.x + threadIdx.x) * 8;
  if (i >= n) return;
  const f32x4 a = *(const f32x4*)(src + i);
  const f32x4 b = *(const f32x4*)(src + i + 4);
  bf16x8 o;
  o[0] = (__bf16)a[0]; o[1] = (__bf16)a[1]; o[2] = (__bf16)a[2]; o[3] = (__bf16)a[3];
  o[4] = (__bf16)b[0]; o[5] = (__bf16)b[1]; o[6] = (__bf16)b[2]; o[7] = (__bf16)b[3];
  *(bf16x8*)(dst + i) = o;
}

extern "C" void kernel_launch(void* const* d_in, const int* in_sizes, int n_in,
                              void* d_out, int out_size, void* d_ws, size_t ws_size,
                              hipStream_t stream) {
  const float* input  = (const float*)d_in[0];
  const float* hidden = (const float*)d_in[1];
  const float* Wzx = (const float*)d_in[2];
  const float* bzx = (const float*)d_in[3];
  const float* Wzh = (const float*)d_in[4];
  const float* Wrx = (const float*)d_in[5];
  const float* brx = (const float*)d_in[6];
  const float* Wrh = (const float*)d_in[7];
  const float* Wgx = (const float*)d_in[8];
  const float* bgx = (const float*)d_in[9];
  const float* Wgh = (const float*)d_in[10];
  const float* Wout = (const float*)d_in[11];
  const float* bout = (const float*)d_in[12];

  float* out = (float*)d_out;
  float* out_hidden = out + HID_OFF;

  char* ws = (char*)d_ws;
  size_t off = 0;
  auto carve = [&](size_t bytes) -> void* {
    off = (off + 255) & ~(size_t)255;
    void* p = ws + off;
    off += bytes;
    return p;
  };

  __bf16* W1t   = (__bf16*)carve(3ull * 1536 * 512 * 2);
  __bf16* Wght  = (__bf16*)carve(3ull * 512 * 512 * 2);
  __bf16* Woutt = (__bf16*)carve(512ull * 512 * 2);
  float*  bias1 = (float*) carve(3ull * 1536 * 4);
  float*  Cterm = (float*) carve(64ull * 1024 * 4);
  const size_t fixed_end = off;

  long chunk_rows = NROWS;
  int C = 1;
  while (C < 32) {
    const size_t need = ((fixed_end + 255) & ~(size_t)255) +
                        5ull * (size_t)chunk_rows * 512 * 2 + 5 * 256;
    if (need <= ws_size) break;
    C *= 2;
    chunk_rows /= 2;
  }
  __bf16* bufA  = (__bf16*)carve((size_t)chunk_rows * 512 * 2);
  __bf16* bufB  = (__bf16*)carve((size_t)chunk_rows * 512 * 2);
  __bf16* zfrag = (__bf16*)carve((size_t)chunk_rows * 512 * 2);
  __bf16* rhb   = (__bf16*)carve((size_t)chunk_rows * 512 * 2);
  __bf16* gfrag = (__bf16*)carve((size_t)chunk_rows * 512 * 2);

  small_prep<<<(3 * 1536 + 64 * 512 + 255) / 256, 256, 0, stream>>>(
      bzx, brx, bgx, hidden, bias1, out_hidden);
  dim3 tp_grid(16, 16, 13), tp_blk(32, 8);
  prep_pack<<<tp_grid, tp_blk, 0, stream>>>(Wzx, Wzh, Wrx, Wrh, Wgx, Wgh, Wout,
                                            W1t, Wght, Woutt);
  cterm_kernel<<<65536 / 256, 256, 0, stream>>>(hidden, Wzh, Wrh, Cterm);

  for (int c = 0; c < C; ++c) {
    const long row_off = (long)c * chunk_rows;
    const long nelem = chunk_rows * 512;
    const int mt = (int)(chunk_rows / 128);

    convert_x<<<(int)((nelem / 8 + 255) / 256), 256, 0, stream>>>(
        input + (size_t)row_off * 512, bufA, nelem);

    // layer 0
    gemm15<0, true><<<mt * 12, 512, 0, stream>>>(
        bufA, W1t, 12, (int)row_off, bias1, Cterm, hidden, nullptr,
        zfrag, gfrag, rhb, nullptr, nullptr);
    gemm15<1, true><<<mt * 4, 512, 0, stream>>>(
        rhb, Wght, 4, (int)row_off, nullptr, nullptr, hidden, nullptr,
        zfrag, gfrag, nullptr, bufB, out_hidden + 512);

    // layer 1 (x == h == bufB)
    gemm15<0, false><<<mt * 12, 512, 0, stream>>>(
        bufB, W1t + 1536 * 512, 12, (int)row_off, bias1 + 1536, nullptr, nullptr, bufB,
        zfrag, gfrag, rhb, nullptr, nullptr);
    gemm15<1, false><<<mt * 4, 512, 0, stream>>>(
        rhb, Wght + 512 * 512, 4, (int)row_off, nullptr, nullptr, nullptr, bufB,
        zfrag, gfrag, nullptr, bufA, out_hidden + 1024);

    // layer 2 (x == h == bufA)
    gemm15<0, false><<<mt * 12, 512, 0, stream>>>(
        bufA, W1t + 2 * 1536 * 512, 12, (int)row_off, bias1 + 3072, nullptr, nullptr, bufA,
        zfrag, gfrag, rhb, nullptr, nullptr);
    gemm15<1, false><<<mt * 4, 512, 0, stream>>>(
        rhb, Wght + 2 * 512 * 512, 4, (int)row_off, nullptr, nullptr, nullptr, bufA,
        zfrag, gfrag, nullptr, bufB, nullptr);

    // output projection
    gemm15<2, false><<<mt * 4, 512, 0, stream>>>(
        bufB, Woutt, 4, (int)row_off, bout, nullptr, nullptr, nullptr,
        nullptr, nullptr, nullptr, nullptr, out + (size_t)row_off * 512);
  }
}

// Round 16
// 903.175 us; speedup vs baseline: 1.9907x; 1.0007x over previous
//
#include <hip/hip_runtime.h>

// MultilayerGRU — reference's indexing bug makes every (b,t) independent:
// 7 chained GEMMs over a 65536x512 activation matrix.
// Round 16: reduce staged bytes WITHOUT lockstep. Gates ingest-wall model:
// time ≈ staged/(15.5 B/cyc/CU). BM=128, BN=256 cuts gates staging 1.54->1.15GB
// (updates 0.51->0.38GB) while keeping 2 blocks/CU of TLP (R14's 256^2 failure
// was 16-wave/1-block lockstep). 8 waves of 64x64 (R12's measured-64-VGPR
// geometry), R12 depth-1 dbuf schedule + verified conflict-free swizzle.

typedef __attribute__((ext_vector_type(4))) float f32x4;
typedef __attribute__((ext_vector_type(8))) __bf16 bf16x8;

#define NROWS 65536          // B*S
#define HID_OFF 33554432ull  // B*S*O floats, start of hidden_out in d_out

__device__ __forceinline__ void gload16(const void* g, void* l) {
  __builtin_amdgcn_global_load_lds((const __attribute__((address_space(1))) void*)g,
                                   (__attribute__((address_space(3))) void*)l,
                                   16, 0, 0);
}
__device__ __forceinline__ float sigmoidf_(float x) { return 1.f / (1.f + __expf(-x)); }
__device__ __forceinline__ float tanh_fast(float x) {
  const float e = __expf(2.f * x);
  return 1.f - 2.f / (e + 1.f);
}

// Stage a 128x32 bf16 A-tile (8KB, 512 chunks) with 512 threads (1 each).
// LDS[row][slot] holds global chunk (slot ^ ((row>>1)&3)) -> 2-way-free reads.
__device__ __forceinline__ void stageA(const __bf16* __restrict__ src, int k0,
                                       __bf16* lds, int w, int lane) {
  const int s = w * 64 + lane;          // chunk 0..511
  const int row = s >> 2;               // 0..127
  const int cc = ((s & 3) ^ (row >> 1)) & 3;
  gload16(src + (size_t)row * 512 + k0 + cc * 8, lds + (w * 64) * 8);
}

// Stage a 256x32 bf16 B-tile (16KB, 1024 chunks) with 512 threads (2 each).
__device__ __forceinline__ void stageB(const __bf16* __restrict__ src, int k0,
                                       __bf16* lds, int w, int lane) {
#pragma unroll
  for (int i = 0; i < 2; ++i) {
    const int s0 = i * 512 + w * 64;
    const int s = s0 + lane;            // chunk 0..1023
    const int row = s >> 2;             // 0..255
    const int cc = ((s & 3) ^ (row >> 1)) & 3;
    gload16(src + (size_t)row * 512 + k0 + cc * 8, lds + s0 * 8);
  }
}

// Swizzled fragment read from a [R][32] tile: slot = (lane>>4) ^ ((row>>1)&3).
__device__ __forceinline__ bf16x8 frag32(const __bf16* t, int row, int lane) {
  const int c = (((lane >> 4) ^ (row >> 1)) & 3);
  return *(const bf16x8*)(t + row * 32 + c * 8);
}

// Stage a 128x256 bf16 tile of haux (512-col row-major) into 64KB LDS (512 thr).
__device__ __forceinline__ void stage_ht(const __bf16* __restrict__ src,
                                         __bf16* Ht, int w, int lane) {
#pragma unroll
  for (int i = 0; i < 8; ++i) {
    const int s0 = i * 512 + w * 64;    // 16B chunks, 32 per row
    const int s = s0 + lane;
    const int row = s >> 5, cc = s & 31;
    gload16(src + (size_t)row * 512 + cc * 8, Ht + s0 * 8);
  }
  asm volatile("s_waitcnt vmcnt(0)");
  __builtin_amdgcn_sched_barrier(0);
  __builtin_amdgcn_s_barrier();
  __builtin_amdgcn_sched_barrier(0);
}

// EPI: 0 = gates (N=1536: z|r|gpart), 1 = update (N=512), 2 = out (N=512)
template<int EPI, bool L0>
__global__ __launch_bounds__(512, 4) void gemm16(
    const __bf16* __restrict__ A,     // M x 512 row-major
    const __bf16* __restrict__ Bt,    // N x 512 (pre-transposed weights)
    int tiles_n, int row_off,
    const float* __restrict__ bias,
    const float* __restrict__ cterm,  // L0 gates: 64 x 1024 fp32
    const float* __restrict__ h0f,    // L0: hidden_state base (B x 3*512)
    const __bf16* __restrict__ haux,  // L>=1: h row-major
    const __bf16* __restrict__ zf,    // relay (EPI0 write / EPI1 read)
    const __bf16* __restrict__ gf,    // relay (EPI0 write / EPI1 read)
    __bf16* __restrict__ o_rh,        // EPI0: r*h row-major
    __bf16* __restrict__ o_h,         // EPI1: h row-major
    float* __restrict__ o_f)          // EPI1: hidden_out slot; EPI2: out
{
  __shared__ alignas(16) __bf16 smem[32768];   // 64KB: kloop 48KB dbuf; epi 64KB
  __bf16* const A0 = smem;                      // 8KB
  __bf16* const B0 = smem + 4096;               // 16KB
  __bf16* const A1 = smem + 12288;              // 8KB
  __bf16* const B1 = smem + 16384;              // 16KB (ends at 24576)

  const int tid = threadIdx.x, lane = tid & 63, w = tid >> 6;
  const int rb = (w >> 2) * 64;   // wave rows: 2 groups of 64
  const int cb = (w & 3) * 64;    // wave cols: 4 groups of 64

  // T1: bijective XCD swizzle (m204)
  int bid = blockIdx.x;
  {
    const int nwg = gridDim.x;
    const int q = nwg >> 3, r = nwg & 7;
    const int x = bid & 7, rest = bid >> 3;
    bid = (x < r ? x * (q + 1) : r * (q + 1) + (x - r) * q) + rest;
  }
  const int tm = bid / tiles_n;
  const int tn = bid - tm * tiles_n;
  const size_t arow0 = (size_t)tm * 128;
  const int brow0 = tn * 256;
  const __bf16* const Ab = A + arow0 * 512;
  const __bf16* const Bb = Bt + (size_t)brow0 * 512;

  f32x4 acc[4][4];
  const f32x4 zz = {0.f, 0.f, 0.f, 0.f};
#pragma unroll
  for (int i = 0; i < 4; ++i)
#pragma unroll
    for (int j = 0; j < 4; ++j) acc[i][j] = zz;

  // depth-1 k-step (R12 schedule): issue stage of tile t+1 first (flies under
  // frag reads + MFMA), compute tile t, drain, barrier.
  auto stepf = [&](int t, const __bf16* cA, const __bf16* cB,
                   __bf16* nA, __bf16* nB) {
    if (t < 15) {
      stageA(Ab, (t + 1) * 32, nA, w, lane);
      stageB(Bb, (t + 1) * 32, nB, w, lane);
    }
    bf16x8 af[4], bf4[4];
#pragma unroll
    for (int i = 0; i < 4; ++i) {
      af[i]  = frag32(cA, rb + i * 16 + (lane & 15), lane);
      bf4[i] = frag32(cB, cb + i * 16 + (lane & 15), lane);
    }
#pragma unroll
    for (int mi = 0; mi < 4; ++mi)
#pragma unroll
      for (int ni = 0; ni < 4; ++ni)
        acc[mi][ni] = __builtin_amdgcn_mfma_f32_16x16x32_bf16(af[mi], bf4[ni], acc[mi][ni], 0, 0, 0);
    if (t < 15) {
      asm volatile("s_waitcnt vmcnt(0)");
      __builtin_amdgcn_sched_barrier(0);
    }
    __builtin_amdgcn_s_barrier();
    __builtin_amdgcn_sched_barrier(0);
  };

  // prologue: tile 0 into slot 0
  stageA(Ab, 0, A0, w, lane);
  stageB(Bb, 0, B0, w, lane);
  asm volatile("s_waitcnt vmcnt(0)");
  __builtin_amdgcn_sched_barrier(0);
  __builtin_amdgcn_s_barrier();
  __builtin_amdgcn_sched_barrier(0);

#pragma unroll 1
  for (int t = 0; t < 16; t += 2) {
    stepf(t,     A0, B0, A1, B1);
    stepf(t + 1, A1, B1, A0, B0);
  }

  // ---------------- epilogues ----------------
  const int fcol = lane & 15;
  const int frow = (lane >> 4) * 4;
  const int bb0 = (row_off + (int)arow0) >> 10;  // batch idx, uniform per tile

  if (EPI == 0) {
    if (tn < 2) {
      // z quadrant (cols 0-511) -> sigmoid, fragment-order relay
      const size_t foff = ((size_t)(tm * 2 + tn)) * 32768 + (size_t)tid * 64;
      __bf16* zw = (__bf16*)zf;
#pragma unroll
      for (int mi = 0; mi < 4; ++mi) {
        bf16x8 p0, p1;
#pragma unroll
        for (int ni = 0; ni < 4; ++ni)
#pragma unroll
          for (int j = 0; j < 4; ++j) {
            const int gcol = brow0 + cb + ni * 16 + fcol;
            float c = acc[mi][ni][j] + bias[gcol];
            if (L0) c += cterm[bb0 * 1024 + gcol];
            const float v = sigmoidf_(c);
            const int idx = ni * 4 + j;
            if (idx < 8) p0[idx] = (__bf16)v; else p1[idx - 8] = (__bf16)v;
          }
        *(bf16x8*)(zw + foff + mi * 16) = p0;
        *(bf16x8*)(zw + foff + mi * 16 + 8) = p1;
      }
    } else if (tn < 4) {
      // r quadrant (cols 512-1023) -> r*h row-major (h LDS-tiled for L>=1)
      if (!L0) stage_ht(haux + arow0 * 512 + (tn - 2) * 256, smem, w, lane);
#pragma unroll
      for (int mi = 0; mi < 4; ++mi)
#pragma unroll
        for (int ni = 0; ni < 4; ++ni)
#pragma unroll
          for (int j = 0; j < 4; ++j) {
            const int rloc = (int)arow0 + rb + mi * 16 + frow + j;
            const int gcol = brow0 + cb + ni * 16 + fcol;
            const int nn = gcol - 512;
            float c = acc[mi][ni][j] + bias[gcol];
            if (L0) c += cterm[bb0 * 1024 + gcol];
            const float rv = sigmoidf_(c);
            const float h = L0 ? h0f[bb0 * 1536 + nn]
                               : (float)smem[(rb + mi * 16 + frow + j) * 256 + cb + ni * 16 + fcol];
            o_rh[(size_t)rloc * 512 + nn] = (__bf16)(rv * h);
          }
    } else {
      // g-partial quadrant (cols 1024-1535) -> fragment-order relay
      const size_t foff = ((size_t)(tm * 2 + (tn - 4))) * 32768 + (size_t)tid * 64;
      __bf16* gw = (__bf16*)gf;
#pragma unroll
      for (int mi = 0; mi < 4; ++mi) {
        bf16x8 p0, p1;
#pragma unroll
        for (int ni = 0; ni < 4; ++ni)
#pragma unroll
          for (int j = 0; j < 4; ++j) {
            const int gcol = brow0 + cb + ni * 16 + fcol;
            const float v = acc[mi][ni][j] + bias[gcol];
            const int idx = ni * 4 + j;
            if (idx < 8) p0[idx] = (__bf16)v; else p1[idx - 8] = (__bf16)v;
          }
        *(bf16x8*)(gw + foff + mi * 16) = p0;
        *(bf16x8*)(gw + foff + mi * 16 + 8) = p1;
      }
    }
  } else if (EPI == 1) {
    // prefetch z/g fragments first (overlaps with stage_ht latency)
    const size_t foff = ((size_t)(tm * 2 + tn)) * 32768 + (size_t)tid * 64;
    bf16x8 zr[4][2], gr[4][2];
#pragma unroll
    for (int mi = 0; mi < 4; ++mi) {
      zr[mi][0] = *(const bf16x8*)(zf + foff + mi * 16);
      zr[mi][1] = *(const bf16x8*)(zf + foff + mi * 16 + 8);
      gr[mi][0] = *(const bf16x8*)(gf + foff + mi * 16);
      gr[mi][1] = *(const bf16x8*)(gf + foff + mi * 16 + 8);
    }
    if (!L0) stage_ht(haux + arow0 * 512 + tn * 256, smem, w, lane);
    const bool has_last = (o_f != nullptr) && ((tm & 7) == 7);
#pragma unroll
    for (int mi = 0; mi < 4; ++mi) {
#pragma unroll
      for (int ni = 0; ni < 4; ++ni)
#pragma unroll
        for (int j = 0; j < 4; ++j) {
          const int rloc = (int)arow0 + rb + mi * 16 + frow + j;
          const int gcol = brow0 + cb + ni * 16 + fcol;
          const int idx = ni * 4 + j;
          const float zv = (float)(idx < 8 ? zr[mi][0][idx] : zr[mi][1][idx - 8]);
          const float gp = (float)(idx < 8 ? gr[mi][0][idx] : gr[mi][1][idx - 8]);
          const float gv = tanh_fast(gp + acc[mi][ni][j]);
          const float h = L0 ? h0f[bb0 * 1536 + gcol]
                             : (float)smem[(rb + mi * 16 + frow + j) * 256 + cb + ni * 16 + fcol];
          const float hv = zv * h + (1.f - zv) * gv;
          o_h[(size_t)rloc * 512 + gcol] = (__bf16)hv;
          if (has_last && ((rloc & 1023) == 1023))
            o_f[(size_t)bb0 * 1536 + gcol] = (float)(__bf16)hv;
        }
    }
  } else {
#pragma unroll
    for (int mi = 0; mi < 4; ++mi)
#pragma unroll
      for (int ni = 0; ni < 4; ++ni)
#pragma unroll
        for (int j = 0; j < 4; ++j) {
          const int rloc = (int)arow0 + rb + mi * 16 + frow + j;
          const int gcol = brow0 + cb + ni * 16 + fcol;
          o_f[(size_t)rloc * 512 + gcol] = acc[mi][ni][j] + bias[gcol];
        }
  }
}

// ---- prep kernels (unchanged, passing) ----

__global__ void prep_pack(const float* __restrict__ Wzx, const float* __restrict__ Wzh,
                          const float* __restrict__ Wrx, const float* __restrict__ Wrh,
                          const float* __restrict__ Wgx, const float* __restrict__ Wgh,
                          const float* __restrict__ Wout,
                          __bf16* __restrict__ W1t, __bf16* __restrict__ Wght,
                          __bf16* __restrict__ Woutt)
{
  const int slot = blockIdx.z;
  const float* srcA;
  const float* srcB = nullptr;
  __bf16* dst;
  if (slot < 9) {
    const int l = slot / 3, g = slot % 3;
    srcA = (g == 0 ? Wzx : g == 1 ? Wrx : Wgx) + (size_t)l * 512 * 512;
    if (l > 0 && g < 2) srcB = (g == 0 ? Wzh : Wrh) + (size_t)l * 512 * 512;
    dst = W1t + (size_t)l * 1536 * 512 + (size_t)g * 512 * 512;
  } else if (slot < 12) {
    const int l = slot - 9;
    srcA = Wgh + (size_t)l * 512 * 512;
    dst = Wght + (size_t)l * 512 * 512;
  } else {
    srcA = Wout;
    dst = Woutt;
  }
  __shared__ float tile[32][33];
  const int k0 = blockIdx.x * 32;
  const int n0 = blockIdx.y * 32;
  const int tx = threadIdx.x;
  const int ty = threadIdx.y;
  for (int i = ty; i < 32; i += 8) {
    float v = srcA[(size_t)(k0 + i) * 512 + n0 + tx];
    if (srcB) v += srcB[(size_t)(k0 + i) * 512 + n0 + tx];
    tile[i][tx] = v;
  }
  __syncthreads();
  for (int i = ty; i < 32; i += 8)
    dst[(size_t)(n0 + i) * 512 + k0 + tx] = (__bf16)tile[tx][i];
}

__global__ void cterm_kernel(const float* __restrict__ hidden,
                             const float* __restrict__ Wzh,
                             const float* __restrict__ Wrh,
                             float* __restrict__ Cterm)
{
  const int idx = blockIdx.x * blockDim.x + threadIdx.x;
  const int b = idx >> 10;
  const int n = idx & 1023;
  const float* W = (n < 512 ? Wzh : Wrh);
  const int nn = n & 511;
  const float* h0 = hidden + (size_t)b * 1536;
  float acc = 0.f;
  for (int k = 0; k < 512; ++k) acc += h0[k] * W[(size_t)k * 512 + nn];
  Cterm[idx] = acc;
}

__global__ void small_prep(const float* __restrict__ bzx, const float* __restrict__ brx,
                           const float* __restrict__ bgx, const float* __restrict__ hidden,
                           float* __restrict__ bias1, float* __restrict__ out_hidden)
{
  const int idx = blockIdx.x * blockDim.x + threadIdx.x;
  if (idx < 3 * 1536) {
    const int l = idx / 1536, j = idx % 1536;
    const float* src = (j < 512 ? bzx : j < 1024 ? brx : bgx);
    bias1[idx] = src[l * 512 + (j & 511)];
  }
  const int hidx = idx - 3 * 1536;
  if (hidx >= 0 && hidx < 64 * 512) {
    const int b = hidx >> 9, n = hidx & 511;
    out_hidden[(size_t)b * 1536 + n] = hidden[(size_t)b * 1536 + n];
  }
}

__global__ void convert_x(const float* __restrict__ src, __bf16* __restrict__ dst, long n)
{
  const long i = ((long)blockIdx.x * blockDim.x + threadIdx.x) * 8;
  if (i >= n) return;
  const f32x4 a = *(const f32x4*)(src + i);
  const f32x4 b = *(const f32x4*)(src + i + 4);
  bf16x8 o;
  o[0] = (__bf16)a[0]; o[1] = (__bf16)a[1]; o[2] = (__bf16)a[2]; o[3] = (__bf16)a[3];
  o[4] = (__bf16)b[0]; o[5] = (__bf16)b[1]; o[6] = (__bf16)b[2]; o[7] = (__bf16)b[3];
  *(bf16x8*)(dst + i) = o;
}

extern "C" void kernel_launch(void* const* d_in, const int* in_sizes, int n_in,
                              void* d_out, int out_size, void* d_ws, size_t ws_size,
                              hipStream_t stream) {
  const float* input  = (const float*)d_in[0];
  const float* hidden = (const float*)d_in[1];
  const float* Wzx = (const float*)d_in[2];
  const float* bzx = (const float*)d_in[3];
  const float* Wzh = (const float*)d_in[4];
  const float* Wrx = (const float*)d_in[5];
  const float* brx = (const float*)d_in[6];
  const float* Wrh = (const float*)d_in[7];
  const float* Wgx = (const float*)d_in[8];
  const float* bgx = (const float*)d_in[9];
  const float* Wgh = (const float*)d_in[10];
  const float* Wout = (const float*)d_in[11];
  const float* bout = (const float*)d_in[12];

  float* out = (float*)d_out;
  float* out_hidden = out + HID_OFF;

  char* ws = (char*)d_ws;
  size_t off = 0;
  auto carve = [&](size_t bytes) -> void* {
    off = (off + 255) & ~(size_t)255;
    void* p = ws + off;
    off += bytes;
    return p;
  };

  __bf16* W1t   = (__bf16*)carve(3ull * 1536 * 512 * 2);
  __bf16* Wght  = (__bf16*)carve(3ull * 512 * 512 * 2);
  __bf16* Woutt = (__bf16*)carve(512ull * 512 * 2);
  float*  bias1 = (float*) carve(3ull * 1536 * 4);
  float*  Cterm = (float*) carve(64ull * 1024 * 4);
  const size_t fixed_end = off;

  long chunk_rows = NROWS;
  int C = 1;
  while (C < 32) {
    const size_t need = ((fixed_end + 255) & ~(size_t)255) +
                        5ull * (size_t)chunk_rows * 512 * 2 + 5 * 256;
    if (need <= ws_size) break;
    C *= 2;
    chunk_rows /= 2;
  }
  __bf16* bufA  = (__bf16*)carve((size_t)chunk_rows * 512 * 2);
  __bf16* bufB  = (__bf16*)carve((size_t)chunk_rows * 512 * 2);
  __bf16* zfrag = (__bf16*)carve((size_t)chunk_rows * 512 * 2);
  __bf16* rhb   = (__bf16*)carve((size_t)chunk_rows * 512 * 2);
  __bf16* gfrag = (__bf16*)carve((size_t)chunk_rows * 512 * 2);

  small_prep<<<(3 * 1536 + 64 * 512 + 255) / 256, 256, 0, stream>>>(
      bzx, brx, bgx, hidden, bias1, out_hidden);
  dim3 tp_grid(16, 16, 13), tp_blk(32, 8);
  prep_pack<<<tp_grid, tp_blk, 0, stream>>>(Wzx, Wzh, Wrx, Wrh, Wgx, Wgh, Wout,
                                            W1t, Wght, Woutt);
  cterm_kernel<<<65536 / 256, 256, 0, stream>>>(hidden, Wzh, Wrh, Cterm);

  for (int c = 0; c < C; ++c) {
    const long row_off = (long)c * chunk_rows;
    const long nelem = chunk_rows * 512;
    const int mt = (int)(chunk_rows / 128);

    convert_x<<<(int)((nelem / 8 + 255) / 256), 256, 0, stream>>>(
        input + (size_t)row_off * 512, bufA, nelem);

    // layer 0
    gemm16<0, true><<<mt * 6, 512, 0, stream>>>(
        bufA, W1t, 6, (int)row_off, bias1, Cterm, hidden, nullptr,
        zfrag, gfrag, rhb, nullptr, nullptr);
    gemm16<1, true><<<mt * 2, 512, 0, stream>>>(
        rhb, Wght, 2, (int)row_off, nullptr, nullptr, hidden, nullptr,
        zfrag, gfrag, nullptr, bufB, out_hidden + 512);

    // layer 1 (x == h == bufB)
    gemm16<0, false><<<mt * 6, 512, 0, stream>>>(
        bufB, W1t + 1536 * 512, 6, (int)row_off, bias1 + 1536, nullptr, nullptr, bufB,
        zfrag, gfrag, rhb, nullptr, nullptr);
    gemm16<1, false><<<mt * 2, 512, 0, stream>>>(
        rhb, Wght + 512 * 512, 2, (int)row_off, nullptr, nullptr, nullptr, bufB,
        zfrag, gfrag, nullptr, bufA, out_hidden + 1024);

    // layer 2 (x == h == bufA)
    gemm16<0, false><<<mt * 6, 512, 0, stream>>>(
        bufA, W1t + 2 * 1536 * 512, 6, (int)row_off, bias1 + 3072, nullptr, nullptr, bufA,
        zfrag, gfrag, rhb, nullptr, nullptr);
    gemm16<1, false><<<mt * 2, 512, 0, stream>>>(
        rhb, Wght + 2 * 512 * 512, 2, (int)row_off, nullptr, nullptr, nullptr, bufA,
        zfrag, gfrag, nullptr, bufB, nullptr);

    // output projection
    gemm16<2, false><<<mt * 2, 512, 0, stream>>>(
        bufB, Woutt, 2, (int)row_off, bout, nullptr, nullptr, nullptr,
        nullptr, nullptr, nullptr, nullptr, out + (size_t)row_off * 512);
  }
}

// Round 17
// 861.917 us; speedup vs baseline: 2.0859x; 1.0479x over previous
//
#include <hip/hip_runtime.h>

// MultilayerGRU — reference's indexing bug makes every (b,t) independent:
// 7 chained GEMMs over a 65536x512 activation matrix.
// FINAL (= round-9 best passing, 863µs): 128x128/BK=32 GEMM, depth-2
// triple-buffered global_load_lds staging with counted vmcnt(4), verified
// 2-way-free LDS swizzle, fragment-order z/g relay between gates and update,
// fused epilogues (sigmoid/tanh_fast/extract_h), bijective XCD swizzle.
// Ten structural variants (R4-R16) all land gates in 165-179µs: balanced
// VALU+LDS-ingest+MFMA floor of this design family.

typedef __attribute__((ext_vector_type(4))) float f32x4;
typedef __attribute__((ext_vector_type(8))) __bf16 bf16x8;

#define NROWS 65536          // B*S
#define HID_OFF 33554432ull  // B*S*O floats, start of hidden_out in d_out

__device__ __forceinline__ void gload16(const void* g, void* l) {
  __builtin_amdgcn_global_load_lds((const __attribute__((address_space(1))) void*)g,
                                   (__attribute__((address_space(3))) void*)l,
                                   16, 0, 0);
}
__device__ __forceinline__ float sigmoidf_(float x) { return 1.f / (1.f + __expf(-x)); }
__device__ __forceinline__ float tanh_fast(float x) {
  const float e = __expf(2.f * x);
  return 1.f - 2.f / (e + 1.f);
}

// Stage one 128x32 bf16 tile (8KB) with 256 threads into linear LDS.
// LDS[row][slot] holds global chunk (slot ^ ((row>>1)&3)) so the swizzled
// read below is bank-conflict-free (each quarter-wave hits all 8 bank-quads
// exactly twice; 2-way is free per m136).
__device__ __forceinline__ void stage32(const __bf16* __restrict__ src, int k0,
                                        __bf16* lds, int w, int lane) {
#pragma unroll
  for (int i = 0; i < 2; ++i) {
    const int s0 = (w * 2 + i) * 64;   // wave-uniform chunk base
    const int s = s0 + lane;           // chunk 0..511
    const int row = s >> 2;            // 0..127
    const int cc = ((s & 3) ^ (row >> 1)) & 3;   // source chunk within row
    gload16(src + (size_t)row * 512 + k0 + cc * 8, lds + s0 * 8);
  }
}

// Swizzled fragment read from a [128][32] tile: slot = (lane>>4) ^ ((row>>1)&3).
__device__ __forceinline__ bf16x8 frag32(const __bf16* t, int row, int lane) {
  const int c = (((lane >> 4) ^ (row >> 1)) & 3);
  return *(const bf16x8*)(t + row * 32 + c * 8);
}

// Stage a 128x128 bf16 tile of haux (512-col row-major) into 32KB LDS.
__device__ __forceinline__ void stage_ht(const __bf16* __restrict__ src,
                                         __bf16* Ht, int w, int lane) {
#pragma unroll
  for (int i = 0; i < 8; ++i) {
    const int s0 = i * 256 + w * 64;   // 16B chunks, 16 per row
    const int s = s0 + lane;
    const int row = s >> 4, cc = s & 15;
    gload16(src + (size_t)row * 512 + cc * 8, Ht + s0 * 8);
  }
  asm volatile("s_waitcnt vmcnt(0)");
  __builtin_amdgcn_sched_barrier(0);
  __builtin_amdgcn_s_barrier();
  __builtin_amdgcn_sched_barrier(0);
}

// EPI: 0 = gates (N=1536: z|r|gpart), 1 = update (N=512), 2 = out (N=512)
template<int EPI, bool L0>
__global__ __launch_bounds__(256, 3) void gemm9(
    const __bf16* __restrict__ A,     // M x 512 row-major
    const __bf16* __restrict__ Bt,    // N x 512 (pre-transposed weights)
    int tiles_n, int row_off,
    const float* __restrict__ bias,
    const float* __restrict__ cterm,  // L0 gates: 64 x 1024 fp32
    const float* __restrict__ h0f,    // L0: hidden_state base (B x 3*512)
    const __bf16* __restrict__ haux,  // L>=1: h row-major
    const __bf16* __restrict__ zf,    // fragment buffer (EPI0 write / EPI1 read)
    const __bf16* __restrict__ gf,    // fragment buffer (EPI0 write / EPI1 read)
    __bf16* __restrict__ o_rh,        // EPI0: r*h row-major
    __bf16* __restrict__ o_h,         // EPI1: h row-major
    float* __restrict__ o_f)          // EPI1: hidden_out slot; EPI2: out
{
  __shared__ alignas(16) __bf16 smem[24576];   // 48KB: 3 x (A 8KB + B 8KB)
  __bf16* const A0 = smem;
  __bf16* const B0 = smem + 4096;
  __bf16* const A1 = smem + 8192;
  __bf16* const B1 = smem + 12288;
  __bf16* const A2 = smem + 16384;
  __bf16* const B2 = smem + 20480;

  const int tid = threadIdx.x, lane = tid & 63, w = tid >> 6;

  // T1: bijective XCD swizzle (m204)
  int bid = blockIdx.x;
  {
    const int nwg = gridDim.x;
    const int q = nwg >> 3, r = nwg & 7;
    const int x = bid & 7, rest = bid >> 3;
    bid = (x < r ? x * (q + 1) : r * (q + 1) + (x - r) * q) + rest;
  }
  const int tm = bid / tiles_n;
  const int tn = bid - tm * tiles_n;
  const size_t arow0 = (size_t)tm * 128;
  const int brow0 = tn * 128;
  const __bf16* const Ab = A + arow0 * 512;
  const __bf16* const Bb = Bt + (size_t)brow0 * 512;

  const int wr = (w >> 1) * 64;
  const int wc = (w & 1) * 64;

  f32x4 acc[4][4];
  const f32x4 zz = {0.f, 0.f, 0.f, 0.f};
#pragma unroll
  for (int i = 0; i < 4; ++i)
#pragma unroll
    for (int j = 0; j < 4; ++j) acc[i][j] = zz;

  // one k-step: stage tile t+2 (depth-2), compute tile t.
  // waits: vm=4 -> tile t+1 landed (t+2's 4 loads stay in flight);
  //        vm=0 -> drain; vm=-1 -> none (last step).
  auto stepf = [&](int t, const __bf16* cA, const __bf16* cB,
                   __bf16* nA, __bf16* nB, int vm) {
    if (nA) {
      stage32(Ab, (t + 2) * 32, nA, w, lane);
      stage32(Bb, (t + 2) * 32, nB, w, lane);
    }
    bf16x8 af[4], bb4[4];
#pragma unroll
    for (int i = 0; i < 4; ++i) {
      af[i]  = frag32(cA, wr + i * 16 + (lane & 15), lane);
      bb4[i] = frag32(cB, wc + i * 16 + (lane & 15), lane);
    }
#pragma unroll
    for (int mi = 0; mi < 4; ++mi)
#pragma unroll
      for (int ni = 0; ni < 4; ++ni)
        acc[mi][ni] = __builtin_amdgcn_mfma_f32_16x16x32_bf16(af[mi], bb4[ni], acc[mi][ni], 0, 0, 0);
    if (vm == 4) {
      asm volatile("s_waitcnt vmcnt(4)");
      __builtin_amdgcn_sched_barrier(0);
    } else if (vm == 0) {
      asm volatile("s_waitcnt vmcnt(0)");
      __builtin_amdgcn_sched_barrier(0);
    }
    __builtin_amdgcn_s_barrier();
    __builtin_amdgcn_sched_barrier(0);
  };

  // prologue: stage tiles 0 and 1 (8 loads/wave); vmcnt(4) -> tile 0 landed,
  // tile 1 (4 loads) still in flight.
  stage32(Ab, 0, A0, w, lane);
  stage32(Bb, 0, B0, w, lane);
  stage32(Ab, 32, A1, w, lane);
  stage32(Bb, 32, B1, w, lane);
  asm volatile("s_waitcnt vmcnt(4)");
  __builtin_amdgcn_sched_barrier(0);
  __builtin_amdgcn_s_barrier();
  __builtin_amdgcn_sched_barrier(0);

  // steps 0..11 (stage tiles 2..13)
#pragma unroll 1
  for (int it = 0; it < 4; ++it) {
    const int t = it * 3;
    stepf(t,     A0, B0, A2, B2, 4);
    stepf(t + 1, A1, B1, A0, B0, 4);
    stepf(t + 2, A2, B2, A1, B1, 4);
  }
  // tail: t=12 stages 14, t=13 stages 15, t=14 drains, t=15 computes last
  stepf(12, A0, B0, A2, B2, 4);
  stepf(13, A1, B1, A0, B0, 4);
  stepf(14, A2, B2, nullptr, nullptr, 0);
  stepf(15, A0, B0, nullptr, nullptr, -1);

  // ---------------- epilogues ----------------
  const int fcol = lane & 15;
  const int frow = (lane >> 4) * 4;
  const int bb0 = (row_off + (int)arow0) >> 10;  // batch idx, uniform per tile

  if (EPI == 0) {
    if (tn < 4) {
      // z quadrant -> fragment-order store
      const size_t foff = ((size_t)(tm * 4 + tn)) * 16384 + (size_t)tid * 64;
      __bf16* zw = (__bf16*)zf;
#pragma unroll
      for (int mi = 0; mi < 4; ++mi) {
        bf16x8 p0, p1;
#pragma unroll
        for (int ni = 0; ni < 4; ++ni)
#pragma unroll
          for (int j = 0; j < 4; ++j) {
            const int gcol = brow0 + wc + ni * 16 + fcol;
            float c = acc[mi][ni][j] + bias[gcol];
            if (L0) c += cterm[bb0 * 1024 + gcol];
            const float v = sigmoidf_(c);
            const int idx = ni * 4 + j;
            if (idx < 8) p0[idx] = (__bf16)v; else p1[idx - 8] = (__bf16)v;
          }
        *(bf16x8*)(zw + foff + mi * 16) = p0;
        *(bf16x8*)(zw + foff + mi * 16 + 8) = p1;
      }
    } else if (tn < 8) {
      // r quadrant -> r*h row-major (h LDS-tiled for L>=1)
      if (!L0) stage_ht(haux + arow0 * 512 + (tn - 4) * 128, smem, w, lane);
#pragma unroll
      for (int mi = 0; mi < 4; ++mi)
#pragma unroll
        for (int ni = 0; ni < 4; ++ni)
#pragma unroll
          for (int j = 0; j < 4; ++j) {
            const int rloc = (int)arow0 + wr + mi * 16 + frow + j;
            const int gcol = brow0 + wc + ni * 16 + fcol;
            const int nn = gcol - 512;
            float c = acc[mi][ni][j] + bias[gcol];
            if (L0) c += cterm[bb0 * 1024 + gcol];
            const float rv = sigmoidf_(c);
            const float h = L0 ? h0f[bb0 * 1536 + nn]
                               : (float)smem[(wr + mi * 16 + frow + j) * 128 + wc + ni * 16 + fcol];
            o_rh[(size_t)rloc * 512 + nn] = (__bf16)(rv * h);
          }
    } else {
      // g-partial quadrant -> fragment-order store (raw, no activation)
      const size_t foff = ((size_t)(tm * 4 + (tn - 8))) * 16384 + (size_t)tid * 64;
      __bf16* gw = (__bf16*)gf;
#pragma unroll
      for (int mi = 0; mi < 4; ++mi) {
        bf16x8 p0, p1;
#pragma unroll
        for (int ni = 0; ni < 4; ++ni)
#pragma unroll
          for (int j = 0; j < 4; ++j) {
            const int gcol = brow0 + wc + ni * 16 + fcol;
            const float v = acc[mi][ni][j] + bias[gcol];
            const int idx = ni * 4 + j;
            if (idx < 8) p0[idx] = (__bf16)v; else p1[idx - 8] = (__bf16)v;
          }
        *(bf16x8*)(gw + foff + mi * 16) = p0;
        *(bf16x8*)(gw + foff + mi * 16 + 8) = p1;
      }
    }
  } else if (EPI == 1) {
    // prefetch z/g fragments first (overlaps with stage_ht latency)
    const size_t foff = ((size_t)(tm * 4 + tn)) * 16384 + (size_t)tid * 64;
    bf16x8 zr[4][2], gr[4][2];
#pragma unroll
    for (int mi = 0; mi < 4; ++mi) {
      zr[mi][0] = *(const bf16x8*)(zf + foff + mi * 16);
      zr[mi][1] = *(const bf16x8*)(zf + foff + mi * 16 + 8);
      gr[mi][0] = *(const bf16x8*)(gf + foff + mi * 16);
      gr[mi][1] = *(const bf16x8*)(gf + foff + mi * 16 + 8);
    }
    if (!L0) stage_ht(haux + arow0 * 512 + tn * 128, smem, w, lane);
    const bool has_last = (o_f != nullptr) && ((tm & 7) == 7);
#pragma unroll
    for (int mi = 0; mi < 4; ++mi) {
#pragma unroll
      for (int ni = 0; ni < 4; ++ni)
#pragma unroll
        for (int j = 0; j < 4; ++j) {
          const int rloc = (int)arow0 + wr + mi * 16 + frow + j;
          const int gcol = brow0 + wc + ni * 16 + fcol;
          const int idx = ni * 4 + j;
          const float zv = (float)(idx < 8 ? zr[mi][0][idx] : zr[mi][1][idx - 8]);
          const float gp = (float)(idx < 8 ? gr[mi][0][idx] : gr[mi][1][idx - 8]);
          const float gv = tanh_fast(gp + acc[mi][ni][j]);
          const float h = L0 ? h0f[bb0 * 1536 + gcol]
                             : (float)smem[(wr + mi * 16 + frow + j) * 128 + wc + ni * 16 + fcol];
          const float hv = zv * h + (1.f - zv) * gv;
          o_h[(size_t)rloc * 512 + gcol] = (__bf16)hv;
          if (has_last && ((rloc & 1023) == 1023))
            o_f[(size_t)bb0 * 1536 + gcol] = (float)(__bf16)hv;
        }
    }
  } else {
#pragma unroll
    for (int mi = 0; mi < 4; ++mi)
#pragma unroll
      for (int ni = 0; ni < 4; ++ni)
#pragma unroll
        for (int j = 0; j < 4; ++j) {
          const int rloc = (int)arow0 + wr + mi * 16 + frow + j;
          const int gcol = brow0 + wc + ni * 16 + fcol;
          o_f[(size_t)rloc * 512 + gcol] = acc[mi][ni][j] + bias[gcol];
        }
  }
}

// ---- prep kernels (unchanged, passing) ----

__global__ void prep_pack(const float* __restrict__ Wzx, const float* __restrict__ Wzh,
                          const float* __restrict__ Wrx, const float* __restrict__ Wrh,
                          const float* __restrict__ Wgx, const float* __restrict__ Wgh,
                          const float* __restrict__ Wout,
                          __bf16* __restrict__ W1t, __bf16* __restrict__ Wght,
                          __bf16* __restrict__ Woutt)
{
  const int slot = blockIdx.z;
  const float* srcA;
  const float* srcB = nullptr;
  __bf16* dst;
  if (slot < 9) {
    const int l = slot / 3, g = slot % 3;
    srcA = (g == 0 ? Wzx : g == 1 ? Wrx : Wgx) + (size_t)l * 512 * 512;
    if (l > 0 && g < 2) srcB = (g == 0 ? Wzh : Wrh) + (size_t)l * 512 * 512;
    dst = W1t + (size_t)l * 1536 * 512 + (size_t)g * 512 * 512;
  } else if (slot < 12) {
    const int l = slot - 9;
    srcA = Wgh + (size_t)l * 512 * 512;
    dst = Wght + (size_t)l * 512 * 512;
  } else {
    srcA = Wout;
    dst = Woutt;
  }
  __shared__ float tile[32][33];
  const int k0 = blockIdx.x * 32;
  const int n0 = blockIdx.y * 32;
  const int tx = threadIdx.x;
  const int ty = threadIdx.y;
  for (int i = ty; i < 32; i += 8) {
    float v = srcA[(size_t)(k0 + i) * 512 + n0 + tx];
    if (srcB) v += srcB[(size_t)(k0 + i) * 512 + n0 + tx];
    tile[i][tx] = v;
  }
  __syncthreads();
  for (int i = ty; i < 32; i += 8)
    dst[(size_t)(n0 + i) * 512 + k0 + tx] = (__bf16)tile[tx][i];
}

__global__ void cterm_kernel(const float* __restrict__ hidden,
                             const float* __restrict__ Wzh,
                             const float* __restrict__ Wrh,
                             float* __restrict__ Cterm)
{
  const int idx = blockIdx.x * blockDim.x + threadIdx.x;
  const int b = idx >> 10;
  const int n = idx & 1023;
  const float* W = (n < 512 ? Wzh : Wrh);
  const int nn = n & 511;
  const float* h0 = hidden + (size_t)b * 1536;
  float acc = 0.f;
  for (int k = 0; k < 512; ++k) acc += h0[k] * W[(size_t)k * 512 + nn];
  Cterm[idx] = acc;
}

__global__ void small_prep(const float* __restrict__ bzx, const float* __restrict__ brx,
                           const float* __restrict__ bgx, const float* __restrict__ hidden,
                           float* __restrict__ bias1, float* __restrict__ out_hidden)
{
  const int idx = blockIdx.x * blockDim.x + threadIdx.x;
  if (idx < 3 * 1536) {
    const int l = idx / 1536, j = idx % 1536;
    const float* src = (j < 512 ? bzx : j < 1024 ? brx : bgx);
    bias1[idx] = src[l * 512 + (j & 511)];
  }
  const int hidx = idx - 3 * 1536;
  if (hidx >= 0 && hidx < 64 * 512) {
    const int b = hidx >> 9, n = hidx & 511;
    out_hidden[(size_t)b * 1536 + n] = hidden[(size_t)b * 1536 + n];
  }
}

__global__ void convert_x(const float* __restrict__ src, __bf16* __restrict__ dst, long n)
{
  const long i = ((long)blockIdx.x * blockDim.x + threadIdx.x) * 8;
  if (i >= n) return;
  const f32x4 a = *(const f32x4*)(src + i);
  const f32x4 b = *(const f32x4*)(src + i + 4);
  bf16x8 o;
  o[0] = (__bf16)a[0]; o[1] = (__bf16)a[1]; o[2] = (__bf16)a[2]; o[3] = (__bf16)a[3];
  o[4] = (__bf16)b[0]; o[5] = (__bf16)b[1]; o[6] = (__bf16)b[2]; o[7] = (__bf16)b[3];
  *(bf16x8*)(dst + i) = o;
}

extern "C" void kernel_launch(void* const* d_in, const int* in_sizes, int n_in,
                              void* d_out, int out_size, void* d_ws, size_t ws_size,
                              hipStream_t stream) {
  const float* input  = (const float*)d_in[0];
  const float* hidden = (const float*)d_in[1];
  const float* Wzx = (const float*)d_in[2];
  const float* bzx = (const float*)d_in[3];
  const float* Wzh = (const float*)d_in[4];
  const float* Wrx = (const float*)d_in[5];
  const float* brx = (const float*)d_in[6];
  const float* Wrh = (const float*)d_in[7];
  const float* Wgx = (const float*)d_in[8];
  const float* bgx = (const float*)d_in[9];
  const float* Wgh = (const float*)d_in[10];
  const float* Wout = (const float*)d_in[11];
  const float* bout = (const float*)d_in[12];

  float* out = (float*)d_out;
  float* out_hidden = out + HID_OFF;

  char* ws = (char*)d_ws;
  size_t off = 0;
  auto carve = [&](size_t bytes) -> void* {
    off = (off + 255) & ~(size_t)255;
    void* p = ws + off;
    off += bytes;
    return p;
  };

  __bf16* W1t   = (__bf16*)carve(3ull * 1536 * 512 * 2);
  __bf16* Wght  = (__bf16*)carve(3ull * 512 * 512 * 2);
  __bf16* Woutt = (__bf16*)carve(512ull * 512 * 2);
  float*  bias1 = (float*) carve(3ull * 1536 * 4);
  float*  Cterm = (float*) carve(64ull * 1024 * 4);
  const size_t fixed_end = off;

  long chunk_rows = NROWS;
  int C = 1;
  while (C < 32) {
    const size_t need = ((fixed_end + 255) & ~(size_t)255) +
                        5ull * (size_t)chunk_rows * 512 * 2 + 5 * 256;
    if (need <= ws_size) break;
    C *= 2;
    chunk_rows /= 2;
  }
  __bf16* bufA  = (__bf16*)carve((size_t)chunk_rows * 512 * 2);
  __bf16* bufB  = (__bf16*)carve((size_t)chunk_rows * 512 * 2);
  __bf16* zfrag = (__bf16*)carve((size_t)chunk_rows * 512 * 2);
  __bf16* rhb   = (__bf16*)carve((size_t)chunk_rows * 512 * 2);
  __bf16* gfrag = (__bf16*)carve((size_t)chunk_rows * 512 * 2);

  small_prep<<<(3 * 1536 + 64 * 512 + 255) / 256, 256, 0, stream>>>(
      bzx, brx, bgx, hidden, bias1, out_hidden);
  dim3 tp_grid(16, 16, 13), tp_blk(32, 8);
  prep_pack<<<tp_grid, tp_blk, 0, stream>>>(Wzx, Wzh, Wrx, Wrh, Wgx, Wgh, Wout,
                                            W1t, Wght, Woutt);
  cterm_kernel<<<65536 / 256, 256, 0, stream>>>(hidden, Wzh, Wrh, Cterm);

  for (int c = 0; c < C; ++c) {
    const long row_off = (long)c * chunk_rows;
    const long nelem = chunk_rows * 512;
    const int mt = (int)(chunk_rows / 128);

    convert_x<<<(int)((nelem / 8 + 255) / 256), 256, 0, stream>>>(
        input + (size_t)row_off * 512, bufA, nelem);

    // layer 0
    gemm9<0, true><<<mt * 12, 256, 0, stream>>>(
        bufA, W1t, 12, (int)row_off, bias1, Cterm, hidden, nullptr,
        zfrag, gfrag, rhb, nullptr, nullptr);
    gemm9<1, true><<<mt * 4, 256, 0, stream>>>(
        rhb, Wght, 4, (int)row_off, nullptr, nullptr, hidden, nullptr,
        zfrag, gfrag, nullptr, bufB, out_hidden + 512);

    // layer 1 (x == h == bufB)
    gemm9<0, false><<<mt * 12, 256, 0, stream>>>(
        bufB, W1t + 1536 * 512, 12, (int)row_off, bias1 + 1536, nullptr, nullptr, bufB,
        zfrag, gfrag, rhb, nullptr, nullptr);
    gemm9<1, false><<<mt * 4, 256, 0, stream>>>(
        rhb, Wght + 512 * 512, 4, (int)row_off, nullptr, nullptr, nullptr, bufB,
        zfrag, gfrag, nullptr, bufA, out_hidden + 1024);

    // layer 2 (x == h == bufA)
    gemm9<0, false><<<mt * 12, 256, 0, stream>>>(
        bufA, W1t + 2 * 1536 * 512, 12, (int)row_off, bias1 + 3072, nullptr, nullptr, bufA,
        zfrag, gfrag, rhb, nullptr, nullptr);
    gemm9<1, false><<<mt * 4, 256, 0, stream>>>(
        rhb, Wght + 2 * 512 * 512, 4, (int)row_off, nullptr, nullptr, nullptr, bufA,
        zfrag, gfrag, nullptr, bufB, nullptr);

    // output projection
    gemm9<2, false><<<mt * 4, 256, 0, stream>>>(
        bufB, Woutt, 4, (int)row_off, bout, nullptr, nullptr, nullptr,
        nullptr, nullptr, nullptr, nullptr, out + (size_t)row_off * 512);
  }
}